// Round 3
// baseline (372.044 us; speedup 1.0000x reference)
//
#include <hip/hip_runtime.h>
#include <hip/hip_bf16.h>

// fp32 in / fp32 out. Internals: single-pass fp16 MFMA.
// Round 3: KEY COMPACTION. Random binary mask kills ~half the keys; masked
// keys contribute exactly 0 to softmax num/denom and PV. Attention is
// permutation-invariant over keys -> compact K and V^T along t (same perm),
// iterate ceil(nkv/64) ~= 17 tiles instead of 32.
//  - scan_mask kernel: per-batch prefix-sum of mask (ballot/popc), writes
//    cpos[b][t] (compacted idx or -1) + nkv[b], zero-fills K/V^T tile tail.
//  - GEMM1 epilogue scatters K/V through cpos (predicated scalar stores).
//  - attn: no mask/smadd at all; last partial tile gates p via cndmask.
//  - cpos/nkv live in d_out scratch (ws is exactly 64 MiB full); stream
//    order scan->gemm1->attn->gemm2; gemm2 overwrites d_out completely.
// Kept from round 2: double-buffered K/V staging, exp2 softmax w/ Q-folded
// scale, setprio, chunked XCD swizzle, GEMM register prefetch.
typedef _Float16 f16;
typedef _Float16 f16x4_t __attribute__((ext_vector_type(4)));
typedef _Float16 f16x8 __attribute__((ext_vector_type(8)));
typedef float f32x4 __attribute__((ext_vector_type(4)));

#define AS1(p) ((const __attribute__((address_space(1))) void*)(p))
#define AS3(p) ((__attribute__((address_space(3))) void*)(p))

__device__ __forceinline__ void gload_lds16(const f16* g, f16* l) {
    __builtin_amdgcn_global_load_lds(AS1(g), AS3(l), 16, 0, 0);
}

__device__ __forceinline__ f16x8 cvt8(float4 u, float4 v) {
    f16x8 r;
    r[0] = (f16)u.x; r[1] = (f16)u.y; r[2] = (f16)u.z; r[3] = (f16)u.w;
    r[4] = (f16)v.x; r[5] = (f16)v.y; r[6] = (f16)v.z; r[7] = (f16)v.w;
    return r;
}

// q pre-scale: 1/sqrt(64) * log2(e) so softmax is exp2(s)
#define Q_SCALE 0.180336880111f

// ---------------------------------------------------------------------------
// scan_mask: per-batch compaction map. 1 wave per batch.
//   cpos[b][t] = compacted index if mask else -1;  nkv[b] = #valid.
// Zero-fills compacted K rows / V^T cols in [nkv, pad64(nkv)) so the attn
// tail tile reads finite zeros (s=0 gated to p=0; V=0 contributes 0).
// ---------------------------------------------------------------------------
__global__ __launch_bounds__(64) void scan_mask(
    const int* __restrict__ mask, int* __restrict__ cpos, int* __restrict__ nkv,
    f16* __restrict__ k_c, f16* __restrict__ vt_c)
{
    const int b = blockIdx.x;          // 4 blocks
    const int lane = threadIdx.x;      // 64 threads
    const int* mb = mask + b * 2048;
    int run = 0;
    for (int c = 0; c < 2048; c += 64) {
        int v = (mb[c + lane] != 0) ? 1 : 0;
        unsigned long long bits = __ballot(v);
        int pre = __popcll(bits & ((1ull << lane) - 1ull));
        cpos[b * 2048 + c + lane] = v ? (run + pre) : -1;
        run += __popcll(bits);
    }
    if (lane == 0) nkv[b] = run;

    const int pad = (run + 63) & ~63;
    const int tail = pad - run;
    if (tail > 0) {
        // K tail: rows [run,pad) x 64 d for each of 16 heads. layout [bh][t][d]
        for (int h = 0; h < 16; ++h) {
            f16* p = &k_c[((size_t)(b * 16 + h) * 2048 + run) * 64];
            for (int x = lane; x < tail * 64; x += 64) p[x] = (f16)0.f;
        }
        // V^T tail: cols [run,pad) for each of 16*64 rows. layout [bh][d][t]
        for (int hd = 0; hd < 16 * 64; ++hd) {
            f16* p = &vt_c[((size_t)(b * 1024 + hd)) * 2048 + run];
            for (int x = lane; x < tail; x += 64) p[x] = (f16)0.f;
        }
    }
}

// ---------------------------------------------------------------------------
// GEMM1: qkv = x @ qkv_w^T + b (fp32 in, fp16 MFMA, fp32 accum), fused repack:
//   q_g f16 [b,h,t,d] (PRE-SCALED) | k_g f16 [b,h,ct,d] | vt_g f16 [b,h,d,ct]
// K/V scattered through cpos (masked keys dropped). 128x128, BK=32, LDK=40.
// ---------------------------------------------------------------------------
__global__ __launch_bounds__(256) void gemm_qkv_f16(
    const float* __restrict__ A, const float* __restrict__ Bw,
    const float* __restrict__ bias, const int* __restrict__ cpos,
    f16* __restrict__ q_g, f16* __restrict__ k_g, f16* __restrict__ vt_g,
    int M, int K)
{
    constexpr int BK = 32, LDK = 40;
    __shared__ f16 As[128 * LDK], Bs[128 * LDK];   // 10 KB each

    const int tid  = threadIdx.x;
    const int lane = tid & 63, wave = tid >> 6;
    const int wy = wave >> 1, wx = wave & 1;
    const int lrow = lane & 15, quad = lane >> 4;
    const size_t m0 = (size_t)blockIdx.y * 128;
    const size_t n0 = (size_t)blockIdx.x * 128;
    const int r0 = tid >> 2;
    const int kc = (tid & 3) * 8;
    const size_t s64K = (size_t)64 * K;

    const float* pa = &A [(m0 + r0) * K + kc];
    const float* pb = &Bw[(n0 + r0) * K + kc];
    float4 a00 = *(const float4*)pa;
    float4 a01 = *(const float4*)(pa + 4);
    float4 a10 = *(const float4*)(pa + s64K);
    float4 a11 = *(const float4*)(pa + s64K + 4);
    float4 b00 = *(const float4*)pb;
    float4 b01 = *(const float4*)(pb + 4);
    float4 b10 = *(const float4*)(pb + s64K);
    float4 b11 = *(const float4*)(pb + s64K + 4);

    f32x4 acc[4][4] = {};

    for (int k0 = 0; k0 < K; k0 += BK) {
        __syncthreads();
        *(f16x8*)&As[ r0       * LDK + kc] = cvt8(a00, a01);
        *(f16x8*)&As[(r0 + 64) * LDK + kc] = cvt8(a10, a11);
        *(f16x8*)&Bs[ r0       * LDK + kc] = cvt8(b00, b01);
        *(f16x8*)&Bs[(r0 + 64) * LDK + kc] = cvt8(b10, b11);
        __syncthreads();

        if (k0 + BK < K) {
            pa += BK; pb += BK;
            a00 = *(const float4*)pa;
            a01 = *(const float4*)(pa + 4);
            a10 = *(const float4*)(pa + s64K);
            a11 = *(const float4*)(pa + s64K + 4);
            b00 = *(const float4*)pb;
            b01 = *(const float4*)(pb + 4);
            b10 = *(const float4*)(pb + s64K);
            b11 = *(const float4*)(pb + s64K + 4);
        }

        f16x8 af[4], bf[4];
#pragma unroll
        for (int i = 0; i < 4; ++i)
            af[i] = *(const f16x8*)&As[(wy * 64 + i * 16 + lrow) * LDK + quad * 8];
#pragma unroll
        for (int j = 0; j < 4; ++j)
            bf[j] = *(const f16x8*)&Bs[(wx * 64 + j * 16 + lrow) * LDK + quad * 8];
#pragma unroll
        for (int i = 0; i < 4; ++i)
#pragma unroll
            for (int j = 0; j < 4; ++j)
                acc[i][j] = __builtin_amdgcn_mfma_f32_16x16x32_f16(af[i], bf[j], acc[i][j], 0, 0, 0);
    }

    // epilogue: C/D layout col=lane&15, row=quad*4+reg; region uniform per block
    const int region = (int)(n0 >> 10);   // 0=q, 1=k, 2=v
#pragma unroll
    for (int i = 0; i < 4; ++i) {
        size_t row = m0 + wy * 64 + i * 16 + quad * 4;
        int b = (int)(row >> 11);
        int t = (int)(row & 2047);
        int cp[4];
        if (region != 0) {
            int4 c4 = *(const int4*)&cpos[b * 2048 + t];
            cp[0] = c4.x; cp[1] = c4.y; cp[2] = c4.z; cp[3] = c4.w;
        }
#pragma unroll
        for (int j = 0; j < 4; ++j) {
            int col = (int)n0 + wx * 64 + j * 16 + lrow;
            float bb = bias[col];
            int cl = col & 1023, hh = cl >> 6, d = cl & 63;
            if (region == 0) {
                size_t o = ((size_t)(b * 16 + hh) * 2048 + t) * 64 + d;
#pragma unroll
                for (int r = 0; r < 4; ++r)
                    q_g[o + (size_t)r * 64] = (f16)((acc[i][j][r] + bb) * Q_SCALE);
            } else if (region == 1) {
#pragma unroll
                for (int r = 0; r < 4; ++r)
                    if (cp[r] >= 0)
                        k_g[((size_t)(b * 16 + hh) * 2048 + cp[r]) * 64 + d] =
                            (f16)(acc[i][j][r] + bb);
            } else {
#pragma unroll
                for (int r = 0; r < 4; ++r)
                    if (cp[r] >= 0)
                        vt_g[((size_t)(b * 16 + hh) * 64 + d) * 2048 + cp[r]] =
                            (f16)(acc[i][j][r] + bb);
            }
        }
    }
}

// ---------------------------------------------------------------------------
// GEMM2: out = att @ out_w^T + b. A is fp16 (b128 direct loads), W fp32->f16.
// ---------------------------------------------------------------------------
__global__ __launch_bounds__(256) void gemm2_f16(
    const f16* __restrict__ A, const float* __restrict__ Bw,
    const float* __restrict__ bias, float* __restrict__ C,
    int M, int N, int K)
{
    constexpr int BK = 32, LDK = 40;
    __shared__ f16 As[128 * LDK], Bs[128 * LDK];

    const int tid  = threadIdx.x;
    const int lane = tid & 63, wave = tid >> 6;
    const int wy = wave >> 1, wx = wave & 1;
    const int lrow = lane & 15, quad = lane >> 4;
    const size_t m0 = (size_t)blockIdx.y * 128;
    const size_t n0 = (size_t)blockIdx.x * 128;
    const int r0 = tid >> 2;
    const int kc = (tid & 3) * 8;
    const size_t s64K = (size_t)64 * K;

    const f16*   pa = &A [(m0 + r0) * K + kc];
    const float* pb = &Bw[(n0 + r0) * K + kc];
    f16x8 ga0 = *(const f16x8*)pa;
    f16x8 ga1 = *(const f16x8*)(pa + s64K);
    float4 b00 = *(const float4*)pb;
    float4 b01 = *(const float4*)(pb + 4);
    float4 b10 = *(const float4*)(pb + s64K);
    float4 b11 = *(const float4*)(pb + s64K + 4);

    f32x4 acc[4][4] = {};

    for (int k0 = 0; k0 < K; k0 += BK) {
        __syncthreads();
        *(f16x8*)&As[ r0       * LDK + kc] = ga0;
        *(f16x8*)&As[(r0 + 64) * LDK + kc] = ga1;
        *(f16x8*)&Bs[ r0       * LDK + kc] = cvt8(b00, b01);
        *(f16x8*)&Bs[(r0 + 64) * LDK + kc] = cvt8(b10, b11);
        __syncthreads();

        if (k0 + BK < K) {
            pa += BK; pb += BK;
            ga0 = *(const f16x8*)pa;
            ga1 = *(const f16x8*)(pa + s64K);
            b00 = *(const float4*)pb;
            b01 = *(const float4*)(pb + 4);
            b10 = *(const float4*)(pb + s64K);
            b11 = *(const float4*)(pb + s64K + 4);
        }

        f16x8 af[4], bf[4];
#pragma unroll
        for (int i = 0; i < 4; ++i)
            af[i] = *(const f16x8*)&As[(wy * 64 + i * 16 + lrow) * LDK + quad * 8];
#pragma unroll
        for (int j = 0; j < 4; ++j)
            bf[j] = *(const f16x8*)&Bs[(wx * 64 + j * 16 + lrow) * LDK + quad * 8];
#pragma unroll
        for (int i = 0; i < 4; ++i)
#pragma unroll
            for (int j = 0; j < 4; ++j)
                acc[i][j] = __builtin_amdgcn_mfma_f32_16x16x32_f16(af[i], bf[j], acc[i][j], 0, 0, 0);
    }

#pragma unroll
    for (int i = 0; i < 4; ++i) {
        size_t row = m0 + wy * 64 + i * 16 + quad * 4;
#pragma unroll
        for (int j = 0; j < 4; ++j) {
            size_t col = n0 + wx * 64 + j * 16 + lrow;
            float bb = bias[col];
#pragma unroll
            for (int r = 0; r < 4; ++r)
                C[(row + r) * N + col] = acc[i][j][r] + bb;
        }
    }
}

// ---------------------------------------------------------------------------
// Attention over COMPACTED keys. Block = (b,h,128 q). ntiles = ceil(nkv/64).
// Double-buffered staging; no mask loads; last partial tile gates p via
// cndmask (tail K/V are zero-filled -> finite).
// ---------------------------------------------------------------------------
__global__ __launch_bounds__(256) void attn_f16(
    const f16* __restrict__ q_g, const f16* __restrict__ k_g,
    const f16* __restrict__ vt_g, const int* __restrict__ nkv,
    f16* __restrict__ att, int B, int T)
{
    constexpr int LDP = 72;
    __shared__ f16 Ks_s[2][64 * 64];    // 16 KB swizzled [key][d], double-buffered
    __shared__ f16 Vt_s[2][64 * 64];    // 16 KB swizzled [d][t], double-buffered
    __shared__ f16 Pt[128 * LDP];       // 18.4 KB [q][key] (wave-private rows)

    const int tid  = threadIdx.x;
    const int lane = tid & 63, wave = tid >> 6;
    const int lrow = lane & 15, quad = lane >> 4;
    // chunked XCD swizzle: 1024 blocks % 8 XCDs == 0 -> bijective.
    const int bid = ((int)blockIdx.x & 7) * 128 + ((int)blockIdx.x >> 3);
    const int qt = bid & 15;
    const int h  = (bid >> 4) & 15;
    const int b  = bid >> 8;
    const size_t base = (size_t)b * T;
    const size_t bh = (size_t)(b * 16 + h);
    const f16* qg_base = q_g  + bh * (2048 * 64);
    const f16* kg_base = k_g  + bh * (2048 * 64);
    const f16* vt_base = vt_g + bh * (64 * 2048);

    const int nk = nkv[b];
    const int ntiles = (nk + 63) >> 6;

    // swizzled frag column offsets (elements)
    const int x0 = ((quad)     ^ (lrow & 7)) * 8;   // k in [0,32)
    const int x1 = ((4 + quad) ^ (lrow & 7)) * 8;   // k in [32,64)

    // ---- Q frags: direct global b128 (A layout: m=lane&15, k=quad*8+j) ----
    f16x8 aq[2][2];
#pragma unroll
    for (int qi = 0; qi < 2; ++qi)
#pragma unroll
        for (int ks = 0; ks < 2; ++ks)
            aq[qi][ks] = *(const f16x8*)&qg_base[
                (size_t)(qt * 128 + wave * 32 + qi * 16 + lrow) * 64 + ks * 32 + quad * 8];

    f32x4 oacc[2][4] = {};        // O^T: [qi][di], rows=d cols=q
    float l_part[2] = {0.f, 0.f};

    const int srow0 = (lane >> 3);   // row within 8-row DMA group
    const int sgrp  = (lane & 7);    // LDS 16B-group

    auto stage = [&](int kt, int bsel) {
        const f16* kT = kg_base + kt * 4096;
#pragma unroll
        for (int j = 0; j < 2; ++j) {
            int rg  = wave + j * 4;               // 8-row group, 0..7
            int row = rg * 8 + srow0;             // key (K) or d (V)
            int grp = sgrp ^ (row & 7);           // swizzled source group
            gload_lds16(&kT[row * 64 + grp * 8], &Ks_s[bsel][rg * 512 + lane * 8]);
            gload_lds16(&vt_base[(size_t)row * 2048 + kt * 64 + grp * 8],
                        &Vt_s[bsel][rg * 512 + lane * 8]);
        }
    };

    stage(0, 0);
    __syncthreads();   // drains vmcnt+lgkm: tile 0 ready

    for (int kt = 0; kt < ntiles; ++kt) {
        const int cur = kt & 1;
        if (kt + 1 < ntiles) stage(kt + 1, cur ^ 1);

        const f16* Ks = Ks_s[cur];
        const f16* Vt = Vt_s[cur];

        // ---- S^T = K . Q^T (1-pass fp16) ----
        f32x4 s[2][4];
        __builtin_amdgcn_s_setprio(1);
#pragma unroll
        for (int ni = 0; ni < 4; ++ni) {
            const int key = ni * 16 + lrow;
            f16x8 k0 = *(const f16x8*)&Ks[key * 64 + x0];
            f16x8 k1 = *(const f16x8*)&Ks[key * 64 + x1];
#pragma unroll
            for (int qi = 0; qi < 2; ++qi) {
                f32x4 t = {0.f, 0.f, 0.f, 0.f};
                t = __builtin_amdgcn_mfma_f32_16x16x32_f16(k0, aq[qi][0], t, 0, 0, 0);
                t = __builtin_amdgcn_mfma_f32_16x16x32_f16(k1, aq[qi][1], t, 0, 0, 0);
                s[qi][ni] = t;
            }
        }
        __builtin_amdgcn_s_setprio(0);

        // ---- max-free softmax: p = exp2(s); all compacted keys valid.
        //      Last partial tile: gate p by key index (tail K/V zero-filled).
        const int rem = nk - kt * 64;
        auto softmax = [&](bool masked) {
#pragma unroll
            for (int qi = 0; qi < 2; ++qi)
#pragma unroll
                for (int ni = 0; ni < 4; ++ni) {
                    float p[4];
#pragma unroll
                    for (int r = 0; r < 4; ++r) {
                        float e = __builtin_amdgcn_exp2f(s[qi][ni][r]);
                        p[r] = (!masked || (ni * 16 + quad * 4 + r) < rem) ? e : 0.f;
                    }
                    l_part[qi] += (p[0] + p[1]) + (p[2] + p[3]);
                    f16x4_t pk;
#pragma unroll
                    for (int r = 0; r < 4; ++r) pk[r] = (f16)p[r];
                    *(f16x4_t*)&Pt[(wave * 32 + qi * 16 + lrow) * LDP + ni * 16 + quad * 4] = pk;
                }
        };
        if (rem >= 64) softmax(false); else softmax(true);

        // ---- O^T += V^T . P^T ----
        f16x8 pf[2][2];
#pragma unroll
        for (int qi = 0; qi < 2; ++qi)
#pragma unroll
            for (int ks = 0; ks < 2; ++ks)
                pf[qi][ks] = *(const f16x8*)&Pt[(wave * 32 + qi * 16 + lrow) * LDP + ks * 32 + quad * 8];
        __builtin_amdgcn_s_setprio(1);
#pragma unroll
        for (int di = 0; di < 4; ++di) {
            const int d = di * 16 + lrow;
            f16x8 v0 = *(const f16x8*)&Vt[d * 64 + x0];
            f16x8 v1 = *(const f16x8*)&Vt[d * 64 + x1];
#pragma unroll
            for (int qi = 0; qi < 2; ++qi) {
                oacc[qi][di] = __builtin_amdgcn_mfma_f32_16x16x32_f16(v0, pf[qi][0], oacc[qi][di], 0, 0, 0);
                oacc[qi][di] = __builtin_amdgcn_mfma_f32_16x16x32_f16(v1, pf[qi][1], oacc[qi][di], 0, 0, 0);
            }
        }
        __builtin_amdgcn_s_setprio(0);

        // single barrier per tile: drains next-tile loads AND protects buffers
        __syncthreads();
    }

    // ---- epilogue: reduce l over quads; att = O^T/l as f16x4 stores ----
#pragma unroll
    for (int qi = 0; qi < 2; ++qi) {
        float v = l_part[qi];
        v += __shfl_xor(v, 16);
        v += __shfl_xor(v, 32);
        float inv = 1.f / v;    // nkv >= 1 always -> l > 0
        int q = qt * 128 + wave * 32 + qi * 16 + lrow;
#pragma unroll
        for (int di = 0; di < 4; ++di) {
            f16x4_t o;
#pragma unroll
            for (int r = 0; r < 4; ++r) o[r] = (f16)(oacc[qi][di][r] * inv);
            *(f16x4_t*)&att[(base + q) * 1024 + h * 64 + di * 16 + quad * 4] = o;
        }
    }
}

// ---------------------------------------------------------------------------
extern "C" void kernel_launch(void* const* d_in, const int* in_sizes, int n_in,
                              void* d_out, int out_size, void* d_ws, size_t ws_size,
                              hipStream_t stream) {
    const float* x     = (const float*)d_in[0];   // [4,2048,1024]
    const int*   mask  = (const int*)d_in[1];     // [4,1,1,2048]
    const float* qkv_w = (const float*)d_in[2];   // [3072,1024]
    const float* qkv_b = (const float*)d_in[3];   // [3072]
    const float* out_w = (const float*)d_in[4];   // [1024,1024]
    const float* out_b = (const float*)d_in[5];   // [1024]
    float* out = (float*)d_out;                   // [4,2048,1024] fp32

    const int B = 4, T = 2048;
    const int M = B * T;                          // 8192
    char* ws = (char*)d_ws;                       // 64 MiB total
    f16* q_g = (f16*)(ws);                        // 16.78 MB [b,h,t,d] (pre-scaled)
    f16* k_g = (f16*)(ws + 16777216);             // 16.78 MB [b,h,ct,d] compacted
    f16* vt  = (f16*)(ws + 33554432);             // 16.78 MB [b,h,d,ct] compacted
    f16* att = (f16*)(ws + 50331648);             // 16.78 MB [t][1024]

    // cpos/nkv scratch lives in d_out (33.5 MB); gemm2 overwrites it last.
    int* cpos = (int*)d_out;                      // 4*2048 ints = 32 KB
    int* nkv  = cpos + 4 * 2048;                  // 4 ints

    dim3 blk(256);
    scan_mask<<<dim3(4), dim3(64), 0, stream>>>(mask, cpos, nkv, k_g, vt);
    gemm_qkv_f16<<<dim3(3072 / 128, M / 128), blk, 0, stream>>>(x, qkv_w, qkv_b, cpos, q_g, k_g, vt, M, 1024);
    attn_f16<<<dim3(B * 16 * 16), blk, 0, stream>>>(q_g, k_g, vt, nkv, att, B, T);
    gemm2_f16<<<dim3(1024 / 128, M / 128), blk, 0, stream>>>(att, out_w, out_b, out, M, 1024, 1024);
}

// Round 4
// 295.627 us; speedup vs baseline: 1.2585x; 1.2585x over previous
//
#include <hip/hip_runtime.h>
#include <hip/hip_bf16.h>

// fp32 in / fp32 out. Internals: single-pass fp16 MFMA.
// Round 4: fix round-3 regression (serial tail-fill ~100us) + XCD swizzle
// on GEMMs.
//  - scan_mask: ballot/prefix scan ONLY (4 blocks x 64 lanes, ~2us).
//  - fill_tail: NEW parallel zero-fill of compacted K/V^T tile tails,
//    grid (4,16) x 256 thr, f16x8 stores for K (contiguous, 128B-aligned).
//  - gemm1/gemm2: chunked XCD swizzle (bijective; 1536%8==0, 512%8==0) so
//    each XCD gets 8 contiguous m-panels -> A working set fits 4MB L2
//    (round-3 counters: FETCH 156MB vs 44MB ideal = per-XCD A re-fetch).
// Kept: key compaction (attn iterates ceil(nkv/64)~17 tiles), double-buffered
// attn staging, exp2 softmax w/ Q-folded scale, setprio, GEMM reg prefetch.
typedef _Float16 f16;
typedef _Float16 f16x4_t __attribute__((ext_vector_type(4)));
typedef _Float16 f16x8 __attribute__((ext_vector_type(8)));
typedef float f32x4 __attribute__((ext_vector_type(4)));

#define AS1(p) ((const __attribute__((address_space(1))) void*)(p))
#define AS3(p) ((__attribute__((address_space(3))) void*)(p))

__device__ __forceinline__ void gload_lds16(const f16* g, f16* l) {
    __builtin_amdgcn_global_load_lds(AS1(g), AS3(l), 16, 0, 0);
}

__device__ __forceinline__ f16x8 cvt8(float4 u, float4 v) {
    f16x8 r;
    r[0] = (f16)u.x; r[1] = (f16)u.y; r[2] = (f16)u.z; r[3] = (f16)u.w;
    r[4] = (f16)v.x; r[5] = (f16)v.y; r[6] = (f16)v.z; r[7] = (f16)v.w;
    return r;
}

// q pre-scale: 1/sqrt(64) * log2(e) so softmax is exp2(s)
#define Q_SCALE 0.180336880111f

// ---------------------------------------------------------------------------
// scan_mask: per-batch compaction map. 1 wave per batch, scan ONLY.
//   cpos[b][t] = compacted index if mask else -1;  nkv[b] = #valid.
// ---------------------------------------------------------------------------
__global__ __launch_bounds__(64) void scan_mask(
    const int* __restrict__ mask, int* __restrict__ cpos, int* __restrict__ nkv)
{
    const int b = blockIdx.x;          // 4 blocks
    const int lane = threadIdx.x;      // 64 threads
    const int* mb = mask + b * 2048;
    int run = 0;
    for (int c = 0; c < 2048; c += 64) {
        int v = (mb[c + lane] != 0) ? 1 : 0;
        unsigned long long bits = __ballot(v);
        int pre = __popcll(bits & ((1ull << lane) - 1ull));
        cpos[b * 2048 + c + lane] = v ? (run + pre) : -1;
        run += __popcll(bits);
    }
    if (lane == 0) nkv[b] = run;
}

// ---------------------------------------------------------------------------
// fill_tail: zero compacted K rows / V^T cols in [nkv, pad64(nkv)) so the
// attn tail tile reads finite zeros. Block = (b,h), 256 threads.
// ---------------------------------------------------------------------------
__global__ __launch_bounds__(256) void fill_tail(
    const int* __restrict__ nkv, f16* __restrict__ k_c, f16* __restrict__ vt_c)
{
    const int b = blockIdx.x, h = blockIdx.y;
    const int run = nkv[b];
    const int pad = (run + 63) & ~63;
    const int tail = pad - run;
    if (tail == 0) return;
    const int tid = threadIdx.x;
    const size_t bh = (size_t)(b * 16 + h);
    // K tail: contiguous [run*64, pad*64) elems per head; run*64 elems = 128B
    // aligned -> f16x8 stores. kn <= 63*64 = 4032 elems.
    f16x8 z = {};
    f16* kp = k_c + bh * (size_t)(2048 * 64) + (size_t)run * 64;
    const int kn = tail * 64;
    for (int x = tid * 8; x < kn; x += 256 * 8)
        *(f16x8*)&kp[x] = z;
    // V^T tail: 64 d-rows, cols [run, pad); lane = col (coalesced per row).
    const int wave = tid >> 6, lane = tid & 63;
    for (int d = wave; d < 64; d += 4) {
        f16* vp = vt_c + (bh * 64 + d) * 2048 + run;
        if (lane < tail) vp[lane] = (f16)0.f;
    }
}

// ---------------------------------------------------------------------------
// GEMM1: qkv = x @ qkv_w^T + b (fp32 in, fp16 MFMA, fp32 accum), fused repack:
//   q_g f16 [b,h,t,d] (PRE-SCALED) | k_g f16 [b,h,ct,d] | vt_g f16 [b,h,d,ct]
// K/V scattered through cpos. 128x128, BK=32, LDK=40. Chunked XCD swizzle.
// ---------------------------------------------------------------------------
__global__ __launch_bounds__(256) void gemm_qkv_f16(
    const float* __restrict__ A, const float* __restrict__ Bw,
    const float* __restrict__ bias, const int* __restrict__ cpos,
    f16* __restrict__ q_g, f16* __restrict__ k_g, f16* __restrict__ vt_g,
    int M, int K)
{
    constexpr int BK = 32, LDK = 40;
    __shared__ f16 As[128 * LDK], Bs[128 * LDK];   // 10 KB each

    const int tid  = threadIdx.x;
    const int lane = tid & 63, wave = tid >> 6;
    const int wy = wave >> 1, wx = wave & 1;
    const int lrow = lane & 15, quad = lane >> 4;
    // chunked XCD swizzle: grid (24,64) = 1536 blocks, 1536%8==0 -> bijective.
    // XCD k gets m-panels [8k, 8k+8): A working set 4MB = one L2.
    const int lin = (int)(blockIdx.y * 24 + blockIdx.x);
    const int swz = (lin & 7) * 192 + (lin >> 3);
    const size_t m0 = (size_t)(swz / 24) * 128;
    const size_t n0 = (size_t)(swz % 24) * 128;
    const int r0 = tid >> 2;
    const int kc = (tid & 3) * 8;
    const size_t s64K = (size_t)64 * K;

    const float* pa = &A [(m0 + r0) * K + kc];
    const float* pb = &Bw[(n0 + r0) * K + kc];
    float4 a00 = *(const float4*)pa;
    float4 a01 = *(const float4*)(pa + 4);
    float4 a10 = *(const float4*)(pa + s64K);
    float4 a11 = *(const float4*)(pa + s64K + 4);
    float4 b00 = *(const float4*)pb;
    float4 b01 = *(const float4*)(pb + 4);
    float4 b10 = *(const float4*)(pb + s64K);
    float4 b11 = *(const float4*)(pb + s64K + 4);

    f32x4 acc[4][4] = {};

    for (int k0 = 0; k0 < K; k0 += BK) {
        __syncthreads();
        *(f16x8*)&As[ r0       * LDK + kc] = cvt8(a00, a01);
        *(f16x8*)&As[(r0 + 64) * LDK + kc] = cvt8(a10, a11);
        *(f16x8*)&Bs[ r0       * LDK + kc] = cvt8(b00, b01);
        *(f16x8*)&Bs[(r0 + 64) * LDK + kc] = cvt8(b10, b11);
        __syncthreads();

        if (k0 + BK < K) {
            pa += BK; pb += BK;
            a00 = *(const float4*)pa;
            a01 = *(const float4*)(pa + 4);
            a10 = *(const float4*)(pa + s64K);
            a11 = *(const float4*)(pa + s64K + 4);
            b00 = *(const float4*)pb;
            b01 = *(const float4*)(pb + 4);
            b10 = *(const float4*)(pb + s64K);
            b11 = *(const float4*)(pb + s64K + 4);
        }

        f16x8 af[4], bf[4];
#pragma unroll
        for (int i = 0; i < 4; ++i)
            af[i] = *(const f16x8*)&As[(wy * 64 + i * 16 + lrow) * LDK + quad * 8];
#pragma unroll
        for (int j = 0; j < 4; ++j)
            bf[j] = *(const f16x8*)&Bs[(wx * 64 + j * 16 + lrow) * LDK + quad * 8];
#pragma unroll
        for (int i = 0; i < 4; ++i)
#pragma unroll
            for (int j = 0; j < 4; ++j)
                acc[i][j] = __builtin_amdgcn_mfma_f32_16x16x32_f16(af[i], bf[j], acc[i][j], 0, 0, 0);
    }

    // epilogue: C/D layout col=lane&15, row=quad*4+reg; region uniform per block
    const int region = (int)(n0 >> 10);   // 0=q, 1=k, 2=v
#pragma unroll
    for (int i = 0; i < 4; ++i) {
        size_t row = m0 + wy * 64 + i * 16 + quad * 4;
        int b = (int)(row >> 11);
        int t = (int)(row & 2047);
        int cp[4];
        if (region != 0) {
            int4 c4 = *(const int4*)&cpos[b * 2048 + t];
            cp[0] = c4.x; cp[1] = c4.y; cp[2] = c4.z; cp[3] = c4.w;
        }
#pragma unroll
        for (int j = 0; j < 4; ++j) {
            int col = (int)n0 + wx * 64 + j * 16 + lrow;
            float bb = bias[col];
            int cl = col & 1023, hh = cl >> 6, d = cl & 63;
            if (region == 0) {
                size_t o = ((size_t)(b * 16 + hh) * 2048 + t) * 64 + d;
#pragma unroll
                for (int r = 0; r < 4; ++r)
                    q_g[o + (size_t)r * 64] = (f16)((acc[i][j][r] + bb) * Q_SCALE);
            } else if (region == 1) {
#pragma unroll
                for (int r = 0; r < 4; ++r)
                    if (cp[r] >= 0)
                        k_g[((size_t)(b * 16 + hh) * 2048 + cp[r]) * 64 + d] =
                            (f16)(acc[i][j][r] + bb);
            } else {
#pragma unroll
                for (int r = 0; r < 4; ++r)
                    if (cp[r] >= 0)
                        vt_g[((size_t)(b * 16 + hh) * 64 + d) * 2048 + cp[r]] =
                            (f16)(acc[i][j][r] + bb);
            }
        }
    }
}

// ---------------------------------------------------------------------------
// GEMM2: out = att @ out_w^T + b. A is fp16 (b128 direct loads), W fp32->f16.
// Chunked XCD swizzle (512 blocks).
// ---------------------------------------------------------------------------
__global__ __launch_bounds__(256) void gemm2_f16(
    const f16* __restrict__ A, const float* __restrict__ Bw,
    const float* __restrict__ bias, float* __restrict__ C,
    int M, int N, int K)
{
    constexpr int BK = 32, LDK = 40;
    __shared__ f16 As[128 * LDK], Bs[128 * LDK];

    const int tid  = threadIdx.x;
    const int lane = tid & 63, wave = tid >> 6;
    const int wy = wave >> 1, wx = wave & 1;
    const int lrow = lane & 15, quad = lane >> 4;
    // chunked XCD swizzle: grid (8,64) = 512 blocks, 512%8==0 -> bijective.
    const int lin = (int)(blockIdx.y * 8 + blockIdx.x);
    const int swz = (lin & 7) * 64 + (lin >> 3);
    const size_t m0 = (size_t)(swz >> 3) * 128;
    const size_t n0 = (size_t)(swz & 7) * 128;
    const int r0 = tid >> 2;
    const int kc = (tid & 3) * 8;
    const size_t s64K = (size_t)64 * K;

    const f16*   pa = &A [(m0 + r0) * K + kc];
    const float* pb = &Bw[(n0 + r0) * K + kc];
    f16x8 ga0 = *(const f16x8*)pa;
    f16x8 ga1 = *(const f16x8*)(pa + s64K);
    float4 b00 = *(const float4*)pb;
    float4 b01 = *(const float4*)(pb + 4);
    float4 b10 = *(const float4*)(pb + s64K);
    float4 b11 = *(const float4*)(pb + s64K + 4);

    f32x4 acc[4][4] = {};

    for (int k0 = 0; k0 < K; k0 += BK) {
        __syncthreads();
        *(f16x8*)&As[ r0       * LDK + kc] = ga0;
        *(f16x8*)&As[(r0 + 64) * LDK + kc] = ga1;
        *(f16x8*)&Bs[ r0       * LDK + kc] = cvt8(b00, b01);
        *(f16x8*)&Bs[(r0 + 64) * LDK + kc] = cvt8(b10, b11);
        __syncthreads();

        if (k0 + BK < K) {
            pa += BK; pb += BK;
            ga0 = *(const f16x8*)pa;
            ga1 = *(const f16x8*)(pa + s64K);
            b00 = *(const float4*)pb;
            b01 = *(const float4*)(pb + 4);
            b10 = *(const float4*)(pb + s64K);
            b11 = *(const float4*)(pb + s64K + 4);
        }

        f16x8 af[4], bf[4];
#pragma unroll
        for (int i = 0; i < 4; ++i)
            af[i] = *(const f16x8*)&As[(wy * 64 + i * 16 + lrow) * LDK + quad * 8];
#pragma unroll
        for (int j = 0; j < 4; ++j)
            bf[j] = *(const f16x8*)&Bs[(wx * 64 + j * 16 + lrow) * LDK + quad * 8];
#pragma unroll
        for (int i = 0; i < 4; ++i)
#pragma unroll
            for (int j = 0; j < 4; ++j)
                acc[i][j] = __builtin_amdgcn_mfma_f32_16x16x32_f16(af[i], bf[j], acc[i][j], 0, 0, 0);
    }

#pragma unroll
    for (int i = 0; i < 4; ++i) {
        size_t row = m0 + wy * 64 + i * 16 + quad * 4;
#pragma unroll
        for (int j = 0; j < 4; ++j) {
            size_t col = n0 + wx * 64 + j * 16 + lrow;
            float bb = bias[col];
#pragma unroll
            for (int r = 0; r < 4; ++r)
                C[(row + r) * N + col] = acc[i][j][r] + bb;
        }
    }
}

// ---------------------------------------------------------------------------
// Attention over COMPACTED keys. Block = (b,h,128 q). ntiles = ceil(nkv/64).
// Double-buffered staging; no mask loads; last partial tile gates p via
// cndmask (tail K/V are zero-filled -> finite).
// ---------------------------------------------------------------------------
__global__ __launch_bounds__(256) void attn_f16(
    const f16* __restrict__ q_g, const f16* __restrict__ k_g,
    const f16* __restrict__ vt_g, const int* __restrict__ nkv,
    f16* __restrict__ att, int B, int T)
{
    constexpr int LDP = 72;
    __shared__ f16 Ks_s[2][64 * 64];    // 16 KB swizzled [key][d], double-buffered
    __shared__ f16 Vt_s[2][64 * 64];    // 16 KB swizzled [d][t], double-buffered
    __shared__ f16 Pt[128 * LDP];       // 18.4 KB [q][key] (wave-private rows)

    const int tid  = threadIdx.x;
    const int lane = tid & 63, wave = tid >> 6;
    const int lrow = lane & 15, quad = lane >> 4;
    // chunked XCD swizzle: 1024 blocks % 8 XCDs == 0 -> bijective.
    const int bid = ((int)blockIdx.x & 7) * 128 + ((int)blockIdx.x >> 3);
    const int qt = bid & 15;
    const int h  = (bid >> 4) & 15;
    const int b  = bid >> 8;
    const size_t base = (size_t)b * T;
    const size_t bh = (size_t)(b * 16 + h);
    const f16* qg_base = q_g  + bh * (2048 * 64);
    const f16* kg_base = k_g  + bh * (2048 * 64);
    const f16* vt_base = vt_g + bh * (64 * 2048);

    const int nk = nkv[b];
    const int ntiles = (nk + 63) >> 6;

    // swizzled frag column offsets (elements)
    const int x0 = ((quad)     ^ (lrow & 7)) * 8;   // k in [0,32)
    const int x1 = ((4 + quad) ^ (lrow & 7)) * 8;   // k in [32,64)

    // ---- Q frags: direct global b128 (A layout: m=lane&15, k=quad*8+j) ----
    f16x8 aq[2][2];
#pragma unroll
    for (int qi = 0; qi < 2; ++qi)
#pragma unroll
        for (int ks = 0; ks < 2; ++ks)
            aq[qi][ks] = *(const f16x8*)&qg_base[
                (size_t)(qt * 128 + wave * 32 + qi * 16 + lrow) * 64 + ks * 32 + quad * 8];

    f32x4 oacc[2][4] = {};        // O^T: [qi][di], rows=d cols=q
    float l_part[2] = {0.f, 0.f};

    const int srow0 = (lane >> 3);   // row within 8-row DMA group
    const int sgrp  = (lane & 7);    // LDS 16B-group

    auto stage = [&](int kt, int bsel) {
        const f16* kT = kg_base + kt * 4096;
#pragma unroll
        for (int j = 0; j < 2; ++j) {
            int rg  = wave + j * 4;               // 8-row group, 0..7
            int row = rg * 8 + srow0;             // key (K) or d (V)
            int grp = sgrp ^ (row & 7);           // swizzled source group
            gload_lds16(&kT[row * 64 + grp * 8], &Ks_s[bsel][rg * 512 + lane * 8]);
            gload_lds16(&vt_base[(size_t)row * 2048 + kt * 64 + grp * 8],
                        &Vt_s[bsel][rg * 512 + lane * 8]);
        }
    };

    stage(0, 0);
    __syncthreads();   // drains vmcnt+lgkm: tile 0 ready

    for (int kt = 0; kt < ntiles; ++kt) {
        const int cur = kt & 1;
        if (kt + 1 < ntiles) stage(kt + 1, cur ^ 1);

        const f16* Ks = Ks_s[cur];
        const f16* Vt = Vt_s[cur];

        // ---- S^T = K . Q^T (1-pass fp16) ----
        f32x4 s[2][4];
        __builtin_amdgcn_s_setprio(1);
#pragma unroll
        for (int ni = 0; ni < 4; ++ni) {
            const int key = ni * 16 + lrow;
            f16x8 k0 = *(const f16x8*)&Ks[key * 64 + x0];
            f16x8 k1 = *(const f16x8*)&Ks[key * 64 + x1];
#pragma unroll
            for (int qi = 0; qi < 2; ++qi) {
                f32x4 t = {0.f, 0.f, 0.f, 0.f};
                t = __builtin_amdgcn_mfma_f32_16x16x32_f16(k0, aq[qi][0], t, 0, 0, 0);
                t = __builtin_amdgcn_mfma_f32_16x16x32_f16(k1, aq[qi][1], t, 0, 0, 0);
                s[qi][ni] = t;
            }
        }
        __builtin_amdgcn_s_setprio(0);

        // ---- max-free softmax: p = exp2(s); all compacted keys valid.
        //      Last partial tile: gate p by key index (tail K/V zero-filled).
        const int rem = nk - kt * 64;
        auto softmax = [&](bool masked) {
#pragma unroll
            for (int qi = 0; qi < 2; ++qi)
#pragma unroll
                for (int ni = 0; ni < 4; ++ni) {
                    float p[4];
#pragma unroll
                    for (int r = 0; r < 4; ++r) {
                        float e = __builtin_amdgcn_exp2f(s[qi][ni][r]);
                        p[r] = (!masked || (ni * 16 + quad * 4 + r) < rem) ? e : 0.f;
                    }
                    l_part[qi] += (p[0] + p[1]) + (p[2] + p[3]);
                    f16x4_t pk;
#pragma unroll
                    for (int r = 0; r < 4; ++r) pk[r] = (f16)p[r];
                    *(f16x4_t*)&Pt[(wave * 32 + qi * 16 + lrow) * LDP + ni * 16 + quad * 4] = pk;
                }
        };
        if (rem >= 64) softmax(false); else softmax(true);

        // ---- O^T += V^T . P^T ----
        f16x8 pf[2][2];
#pragma unroll
        for (int qi = 0; qi < 2; ++qi)
#pragma unroll
            for (int ks = 0; ks < 2; ++ks)
                pf[qi][ks] = *(const f16x8*)&Pt[(wave * 32 + qi * 16 + lrow) * LDP + ks * 32 + quad * 8];
        __builtin_amdgcn_s_setprio(1);
#pragma unroll
        for (int di = 0; di < 4; ++di) {
            const int d = di * 16 + lrow;
            f16x8 v0 = *(const f16x8*)&Vt[d * 64 + x0];
            f16x8 v1 = *(const f16x8*)&Vt[d * 64 + x1];
#pragma unroll
            for (int qi = 0; qi < 2; ++qi) {
                oacc[qi][di] = __builtin_amdgcn_mfma_f32_16x16x32_f16(v0, pf[qi][0], oacc[qi][di], 0, 0, 0);
                oacc[qi][di] = __builtin_amdgcn_mfma_f32_16x16x32_f16(v1, pf[qi][1], oacc[qi][di], 0, 0, 0);
            }
        }
        __builtin_amdgcn_s_setprio(0);

        // single barrier per tile: drains next-tile loads AND protects buffers
        __syncthreads();
    }

    // ---- epilogue: reduce l over quads; att = O^T/l as f16x4 stores ----
#pragma unroll
    for (int qi = 0; qi < 2; ++qi) {
        float v = l_part[qi];
        v += __shfl_xor(v, 16);
        v += __shfl_xor(v, 32);
        float inv = 1.f / v;    // nkv >= 1 always -> l > 0
        int q = qt * 128 + wave * 32 + qi * 16 + lrow;
#pragma unroll
        for (int di = 0; di < 4; ++di) {
            f16x4_t o;
#pragma unroll
            for (int r = 0; r < 4; ++r) o[r] = (f16)(oacc[qi][di][r] * inv);
            *(f16x4_t*)&att[(base + q) * 1024 + h * 64 + di * 16 + quad * 4] = o;
        }
    }
}

// ---------------------------------------------------------------------------
extern "C" void kernel_launch(void* const* d_in, const int* in_sizes, int n_in,
                              void* d_out, int out_size, void* d_ws, size_t ws_size,
                              hipStream_t stream) {
    const float* x     = (const float*)d_in[0];   // [4,2048,1024]
    const int*   mask  = (const int*)d_in[1];     // [4,1,1,2048]
    const float* qkv_w = (const float*)d_in[2];   // [3072,1024]
    const float* qkv_b = (const float*)d_in[3];   // [3072]
    const float* out_w = (const float*)d_in[4];   // [1024,1024]
    const float* out_b = (const float*)d_in[5];   // [1024]
    float* out = (float*)d_out;                   // [4,2048,1024] fp32

    const int B = 4, T = 2048;
    const int M = B * T;                          // 8192
    char* ws = (char*)d_ws;                       // 64 MiB total
    f16* q_g = (f16*)(ws);                        // 16.78 MB [b,h,t,d] (pre-scaled)
    f16* k_g = (f16*)(ws + 16777216);             // 16.78 MB [b,h,ct,d] compacted
    f16* vt  = (f16*)(ws + 33554432);             // 16.78 MB [b,h,d,ct] compacted
    f16* att = (f16*)(ws + 50331648);             // 16.78 MB [t][1024]

    // cpos/nkv scratch lives in d_out (33.5 MB); gemm2 overwrites it last.
    int* cpos = (int*)d_out;                      // 4*2048 ints = 32 KB
    int* nkv  = cpos + 4 * 2048;                  // 4 ints

    dim3 blk(256);
    scan_mask<<<dim3(4), dim3(64), 0, stream>>>(mask, cpos, nkv);
    fill_tail<<<dim3(4, 16), blk, 0, stream>>>(nkv, k_g, vt);
    gemm_qkv_f16<<<dim3(3072 / 128, M / 128), blk, 0, stream>>>(x, qkv_w, qkv_b, cpos, q_g, k_g, vt, M, 1024);
    attn_f16<<<dim3(B * 16 * 16), blk, 0, stream>>>(q_g, k_g, vt, nkv, att, B, T);
    gemm2_f16<<<dim3(1024 / 128, M / 128), blk, 0, stream>>>(att, out_w, out_b, out, M, 1024, 1024);
}

// Round 5
// 279.459 us; speedup vs baseline: 1.3313x; 1.0579x over previous
//
#include <hip/hip_runtime.h>
#include <hip/hip_bf16.h>

// fp32 in / fp32 out. Internals: single-pass fp16 MFMA.
// Round 5: m97-structure GEMMs.
//  - REVERT gemm XCD swizzle (round-4 counters: FETCH 156->240MB, dur +6us
//    -> chunking theory wrong; natural x-fastest order has better locality).
//  - cvt_f32_f16 pre-pass: x,qkv_w -> f16 in d_out scratch; out_w -> f16
//    into dead q_g region after attn. ~12us of pure BW.
//  - GEMMs: BK=64, global_load_lds width-16 staging (no VGPR roundtrip, no
//    cvt in loop), XOR source-swizzle + swizzled ds_read (same involution as
//    attn staging; fixes 12.6M bank conflicts; padding illegal w/ gload_lds).
// Kept: key compaction, parallel fill_tail, attn kernel verbatim (dbuf
// staging, exp2 softmax, setprio, XCD swizzle - measured FETCH win there).
typedef _Float16 f16;
typedef _Float16 f16x4_t __attribute__((ext_vector_type(4)));
typedef _Float16 f16x8 __attribute__((ext_vector_type(8)));
typedef float f32x4 __attribute__((ext_vector_type(4)));

#define AS1(p) ((const __attribute__((address_space(1))) void*)(p))
#define AS3(p) ((__attribute__((address_space(3))) void*)(p))

__device__ __forceinline__ void gload_lds16(const f16* g, f16* l) {
    __builtin_amdgcn_global_load_lds(AS1(g), AS3(l), 16, 0, 0);
}

__device__ __forceinline__ f16x8 cvt8(float4 u, float4 v) {
    f16x8 r;
    r[0] = (f16)u.x; r[1] = (f16)u.y; r[2] = (f16)u.z; r[3] = (f16)u.w;
    r[4] = (f16)v.x; r[5] = (f16)v.y; r[6] = (f16)v.z; r[7] = (f16)v.w;
    return r;
}

// q pre-scale: 1/sqrt(64) * log2(e) so softmax is exp2(s)
#define Q_SCALE 0.180336880111f

// ---------------------------------------------------------------------------
// cvt_f32_f16: vectorized fp32 -> fp16, n8 = count/8 (all sizes divide by 8).
// ---------------------------------------------------------------------------
__global__ __launch_bounds__(256) void cvt_f32_f16(
    const float* __restrict__ src, f16* __restrict__ dst, int n8)
{
    int idx = blockIdx.x * 256 + threadIdx.x;
    int stride = gridDim.x * 256;
    for (int i = idx; i < n8; i += stride) {
        size_t o = (size_t)i * 8;
        float4 u = *(const float4*)&src[o];
        float4 v = *(const float4*)&src[o + 4];
        *(f16x8*)&dst[o] = cvt8(u, v);
    }
}

// ---------------------------------------------------------------------------
// scan_mask: per-batch compaction map. 1 wave per batch, scan ONLY.
// ---------------------------------------------------------------------------
__global__ __launch_bounds__(64) void scan_mask(
    const int* __restrict__ mask, int* __restrict__ cpos, int* __restrict__ nkv)
{
    const int b = blockIdx.x;          // 4 blocks
    const int lane = threadIdx.x;      // 64 threads
    const int* mb = mask + b * 2048;
    int run = 0;
    for (int c = 0; c < 2048; c += 64) {
        int v = (mb[c + lane] != 0) ? 1 : 0;
        unsigned long long bits = __ballot(v);
        int pre = __popcll(bits & ((1ull << lane) - 1ull));
        cpos[b * 2048 + c + lane] = v ? (run + pre) : -1;
        run += __popcll(bits);
    }
    if (lane == 0) nkv[b] = run;
}

// ---------------------------------------------------------------------------
// fill_tail: zero compacted K rows / V^T cols in [nkv, pad64(nkv)).
// ---------------------------------------------------------------------------
__global__ __launch_bounds__(256) void fill_tail(
    const int* __restrict__ nkv, f16* __restrict__ k_c, f16* __restrict__ vt_c)
{
    const int b = blockIdx.x, h = blockIdx.y;
    const int run = nkv[b];
    const int pad = (run + 63) & ~63;
    const int tail = pad - run;
    if (tail == 0) return;
    const int tid = threadIdx.x;
    const size_t bh = (size_t)(b * 16 + h);
    f16x8 z = {};
    f16* kp = k_c + bh * (size_t)(2048 * 64) + (size_t)run * 64;
    const int kn = tail * 64;
    for (int x = tid * 8; x < kn; x += 256 * 8)
        *(f16x8*)&kp[x] = z;
    const int wave = tid >> 6, lane = tid & 63;
    for (int d = wave; d < 64; d += 4) {
        f16* vp = vt_c + (bh * 64 + d) * 2048 + run;
        if (lane < tail) vp[lane] = (f16)0.f;
    }
}

// ---------------------------------------------------------------------------
// GEMM1: qkv = x16 @ w16^T + b (f16 MFMA, fp32 accum), fused repack:
//   q_g f16 [b,h,t,d] (PRE-SCALED) | k_g f16 [b,h,ct,d] | vt_g f16 [b,h,d,ct]
// 128x128 tile, BK=64, global_load_lds staging w/ XOR swizzle.
// ---------------------------------------------------------------------------
__global__ __launch_bounds__(256) void gemm_qkv_f16(
    const f16* __restrict__ A16, const f16* __restrict__ Bw16,
    const float* __restrict__ bias, const int* __restrict__ cpos,
    f16* __restrict__ q_g, f16* __restrict__ k_g, f16* __restrict__ vt_g,
    int M, int K)
{
    constexpr int BK = 64;
    __shared__ f16 As[128 * BK], Bs[128 * BK];   // 16 KB each

    const int tid  = threadIdx.x;
    const int lane = tid & 63, wave = tid >> 6;
    const int wy = wave >> 1, wx = wave & 1;
    const int lrow = lane & 15, quad = lane >> 4;
    const size_t m0 = (size_t)blockIdx.y * 128;
    const size_t n0 = (size_t)blockIdx.x * 128;
    const int srow = lane >> 3;       // row within 8-row DMA group
    const int sgrp = lane & 7;        // LDS 16B-group
    // swizzled frag column offsets (f16 elements)
    const int x0 = ((quad)     ^ (lrow & 7)) * 8;   // k in [0,32)
    const int x1 = ((4 + quad) ^ (lrow & 7)) * 8;   // k in [32,64)

    f32x4 acc[4][4] = {};

    for (int k0 = 0; k0 < K; k0 += BK) {
        __syncthreads();               // all waves done reading prev tile
#pragma unroll
        for (int j = 0; j < 4; ++j) {
            int rg  = wave * 4 + j;            // 16 groups of 8 rows
            int row = rg * 8 + srow;
            int grp = sgrp ^ srow;             // row&7 == srow
            gload_lds16(&A16[(m0 + row) * (size_t)K + k0 + grp * 8],
                        &As[rg * 512 + lane * 8]);
            gload_lds16(&Bw16[(n0 + row) * (size_t)K + k0 + grp * 8],
                        &Bs[rg * 512 + lane * 8]);
        }
        __syncthreads();               // drains vmcnt: tile staged

        f16x8 a0[4], a1[4], b0[4], b1[4];
#pragma unroll
        for (int i = 0; i < 4; ++i) {
            const int r = (wy * 64 + i * 16 + lrow) * BK;
            a0[i] = *(const f16x8*)&As[r + x0];
            a1[i] = *(const f16x8*)&As[r + x1];
        }
#pragma unroll
        for (int j = 0; j < 4; ++j) {
            const int r = (wx * 64 + j * 16 + lrow) * BK;
            b0[j] = *(const f16x8*)&Bs[r + x0];
            b1[j] = *(const f16x8*)&Bs[r + x1];
        }
#pragma unroll
        for (int i = 0; i < 4; ++i)
#pragma unroll
            for (int j = 0; j < 4; ++j) {
                acc[i][j] = __builtin_amdgcn_mfma_f32_16x16x32_f16(a0[i], b0[j], acc[i][j], 0, 0, 0);
                acc[i][j] = __builtin_amdgcn_mfma_f32_16x16x32_f16(a1[i], b1[j], acc[i][j], 0, 0, 0);
            }
    }

    // epilogue: C/D layout col=lane&15, row=quad*4+reg; region uniform per block
    const int region = (int)(n0 >> 10);   // 0=q, 1=k, 2=v
#pragma unroll
    for (int i = 0; i < 4; ++i) {
        size_t row = m0 + wy * 64 + i * 16 + quad * 4;
        int b = (int)(row >> 11);
        int t = (int)(row & 2047);
        int cp[4];
        if (region != 0) {
            int4 c4 = *(const int4*)&cpos[b * 2048 + t];
            cp[0] = c4.x; cp[1] = c4.y; cp[2] = c4.z; cp[3] = c4.w;
        }
#pragma unroll
        for (int j = 0; j < 4; ++j) {
            int col = (int)n0 + wx * 64 + j * 16 + lrow;
            float bb = bias[col];
            int cl = col & 1023, hh = cl >> 6, d = cl & 63;
            if (region == 0) {
                size_t o = ((size_t)(b * 16 + hh) * 2048 + t) * 64 + d;
#pragma unroll
                for (int r = 0; r < 4; ++r)
                    q_g[o + (size_t)r * 64] = (f16)((acc[i][j][r] + bb) * Q_SCALE);
            } else if (region == 1) {
#pragma unroll
                for (int r = 0; r < 4; ++r)
                    if (cp[r] >= 0)
                        k_g[((size_t)(b * 16 + hh) * 2048 + cp[r]) * 64 + d] =
                            (f16)(acc[i][j][r] + bb);
            } else {
#pragma unroll
                for (int r = 0; r < 4; ++r)
                    if (cp[r] >= 0)
                        vt_g[((size_t)(b * 16 + hh) * 64 + d) * 2048 + cp[r]] =
                            (f16)(acc[i][j][r] + bb);
            }
        }
    }
}

// ---------------------------------------------------------------------------
// GEMM2: out = att @ ow16^T + b (all-f16 inputs, fp32 out). Same structure.
// ---------------------------------------------------------------------------
__global__ __launch_bounds__(256) void gemm2_f16(
    const f16* __restrict__ A16, const f16* __restrict__ Bw16,
    const float* __restrict__ bias, float* __restrict__ C,
    int M, int N, int K)
{
    constexpr int BK = 64;
    __shared__ f16 As[128 * BK], Bs[128 * BK];

    const int tid  = threadIdx.x;
    const int lane = tid & 63, wave = tid >> 6;
    const int wy = wave >> 1, wx = wave & 1;
    const int lrow = lane & 15, quad = lane >> 4;
    const size_t m0 = (size_t)blockIdx.y * 128;
    const size_t n0 = (size_t)blockIdx.x * 128;
    const int srow = lane >> 3, sgrp = lane & 7;
    const int x0 = ((quad)     ^ (lrow & 7)) * 8;
    const int x1 = ((4 + quad) ^ (lrow & 7)) * 8;

    f32x4 acc[4][4] = {};

    for (int k0 = 0; k0 < K; k0 += BK) {
        __syncthreads();
#pragma unroll
        for (int j = 0; j < 4; ++j) {
            int rg  = wave * 4 + j;
            int row = rg * 8 + srow;
            int grp = sgrp ^ srow;
            gload_lds16(&A16[(m0 + row) * (size_t)K + k0 + grp * 8],
                        &As[rg * 512 + lane * 8]);
            gload_lds16(&Bw16[(n0 + row) * (size_t)K + k0 + grp * 8],
                        &Bs[rg * 512 + lane * 8]);
        }
        __syncthreads();

        f16x8 a0[4], a1[4], b0[4], b1[4];
#pragma unroll
        for (int i = 0; i < 4; ++i) {
            const int r = (wy * 64 + i * 16 + lrow) * BK;
            a0[i] = *(const f16x8*)&As[r + x0];
            a1[i] = *(const f16x8*)&As[r + x1];
        }
#pragma unroll
        for (int j = 0; j < 4; ++j) {
            const int r = (wx * 64 + j * 16 + lrow) * BK;
            b0[j] = *(const f16x8*)&Bs[r + x0];
            b1[j] = *(const f16x8*)&Bs[r + x1];
        }
#pragma unroll
        for (int i = 0; i < 4; ++i)
#pragma unroll
            for (int j = 0; j < 4; ++j) {
                acc[i][j] = __builtin_amdgcn_mfma_f32_16x16x32_f16(a0[i], b0[j], acc[i][j], 0, 0, 0);
                acc[i][j] = __builtin_amdgcn_mfma_f32_16x16x32_f16(a1[i], b1[j], acc[i][j], 0, 0, 0);
            }
    }

#pragma unroll
    for (int i = 0; i < 4; ++i) {
        size_t row = m0 + wy * 64 + i * 16 + quad * 4;
#pragma unroll
        for (int j = 0; j < 4; ++j) {
            size_t col = n0 + wx * 64 + j * 16 + lrow;
            float bb = bias[col];
#pragma unroll
            for (int r = 0; r < 4; ++r)
                C[(row + r) * N + col] = acc[i][j][r] + bb;
        }
    }
}

// ---------------------------------------------------------------------------
// Attention over COMPACTED keys (verbatim from round 4 - passing).
// ---------------------------------------------------------------------------
__global__ __launch_bounds__(256) void attn_f16(
    const f16* __restrict__ q_g, const f16* __restrict__ k_g,
    const f16* __restrict__ vt_g, const int* __restrict__ nkv,
    f16* __restrict__ att, int B, int T)
{
    constexpr int LDP = 72;
    __shared__ f16 Ks_s[2][64 * 64];
    __shared__ f16 Vt_s[2][64 * 64];
    __shared__ f16 Pt[128 * LDP];

    const int tid  = threadIdx.x;
    const int lane = tid & 63, wave = tid >> 6;
    const int lrow = lane & 15, quad = lane >> 4;
    const int bid = ((int)blockIdx.x & 7) * 128 + ((int)blockIdx.x >> 3);
    const int qt = bid & 15;
    const int h  = (bid >> 4) & 15;
    const int b  = bid >> 8;
    const size_t base = (size_t)b * T;
    const size_t bh = (size_t)(b * 16 + h);
    const f16* qg_base = q_g  + bh * (2048 * 64);
    const f16* kg_base = k_g  + bh * (2048 * 64);
    const f16* vt_base = vt_g + bh * (64 * 2048);

    const int nk = nkv[b];
    const int ntiles = (nk + 63) >> 6;

    const int x0 = ((quad)     ^ (lrow & 7)) * 8;
    const int x1 = ((4 + quad) ^ (lrow & 7)) * 8;

    f16x8 aq[2][2];
#pragma unroll
    for (int qi = 0; qi < 2; ++qi)
#pragma unroll
        for (int ks = 0; ks < 2; ++ks)
            aq[qi][ks] = *(const f16x8*)&qg_base[
                (size_t)(qt * 128 + wave * 32 + qi * 16 + lrow) * 64 + ks * 32 + quad * 8];

    f32x4 oacc[2][4] = {};
    float l_part[2] = {0.f, 0.f};

    const int srow0 = (lane >> 3);
    const int sgrp  = (lane & 7);

    auto stage = [&](int kt, int bsel) {
        const f16* kT = kg_base + kt * 4096;
#pragma unroll
        for (int j = 0; j < 2; ++j) {
            int rg  = wave + j * 4;
            int row = rg * 8 + srow0;
            int grp = sgrp ^ (row & 7);
            gload_lds16(&kT[row * 64 + grp * 8], &Ks_s[bsel][rg * 512 + lane * 8]);
            gload_lds16(&vt_base[(size_t)row * 2048 + kt * 64 + grp * 8],
                        &Vt_s[bsel][rg * 512 + lane * 8]);
        }
    };

    stage(0, 0);
    __syncthreads();

    for (int kt = 0; kt < ntiles; ++kt) {
        const int cur = kt & 1;
        if (kt + 1 < ntiles) stage(kt + 1, cur ^ 1);

        const f16* Ks = Ks_s[cur];
        const f16* Vt = Vt_s[cur];

        f32x4 s[2][4];
        __builtin_amdgcn_s_setprio(1);
#pragma unroll
        for (int ni = 0; ni < 4; ++ni) {
            const int key = ni * 16 + lrow;
            f16x8 k0 = *(const f16x8*)&Ks[key * 64 + x0];
            f16x8 k1 = *(const f16x8*)&Ks[key * 64 + x1];
#pragma unroll
            for (int qi = 0; qi < 2; ++qi) {
                f32x4 t = {0.f, 0.f, 0.f, 0.f};
                t = __builtin_amdgcn_mfma_f32_16x16x32_f16(k0, aq[qi][0], t, 0, 0, 0);
                t = __builtin_amdgcn_mfma_f32_16x16x32_f16(k1, aq[qi][1], t, 0, 0, 0);
                s[qi][ni] = t;
            }
        }
        __builtin_amdgcn_s_setprio(0);

        const int rem = nk - kt * 64;
        auto softmax = [&](bool masked) {
#pragma unroll
            for (int qi = 0; qi < 2; ++qi)
#pragma unroll
                for (int ni = 0; ni < 4; ++ni) {
                    float p[4];
#pragma unroll
                    for (int r = 0; r < 4; ++r) {
                        float e = __builtin_amdgcn_exp2f(s[qi][ni][r]);
                        p[r] = (!masked || (ni * 16 + quad * 4 + r) < rem) ? e : 0.f;
                    }
                    l_part[qi] += (p[0] + p[1]) + (p[2] + p[3]);
                    f16x4_t pk;
#pragma unroll
                    for (int r = 0; r < 4; ++r) pk[r] = (f16)p[r];
                    *(f16x4_t*)&Pt[(wave * 32 + qi * 16 + lrow) * LDP + ni * 16 + quad * 4] = pk;
                }
        };
        if (rem >= 64) softmax(false); else softmax(true);

        f16x8 pf[2][2];
#pragma unroll
        for (int qi = 0; qi < 2; ++qi)
#pragma unroll
            for (int ks = 0; ks < 2; ++ks)
                pf[qi][ks] = *(const f16x8*)&Pt[(wave * 32 + qi * 16 + lrow) * LDP + ks * 32 + quad * 8];
        __builtin_amdgcn_s_setprio(1);
#pragma unroll
        for (int di = 0; di < 4; ++di) {
            const int d = di * 16 + lrow;
            f16x8 v0 = *(const f16x8*)&Vt[d * 64 + x0];
            f16x8 v1 = *(const f16x8*)&Vt[d * 64 + x1];
#pragma unroll
            for (int qi = 0; qi < 2; ++qi) {
                oacc[qi][di] = __builtin_amdgcn_mfma_f32_16x16x32_f16(v0, pf[qi][0], oacc[qi][di], 0, 0, 0);
                oacc[qi][di] = __builtin_amdgcn_mfma_f32_16x16x32_f16(v1, pf[qi][1], oacc[qi][di], 0, 0, 0);
            }
        }
        __builtin_amdgcn_s_setprio(0);

        __syncthreads();
    }

#pragma unroll
    for (int qi = 0; qi < 2; ++qi) {
        float v = l_part[qi];
        v += __shfl_xor(v, 16);
        v += __shfl_xor(v, 32);
        float inv = 1.f / v;
        int q = qt * 128 + wave * 32 + qi * 16 + lrow;
#pragma unroll
        for (int di = 0; di < 4; ++di) {
            f16x4_t o;
#pragma unroll
            for (int r = 0; r < 4; ++r) o[r] = (f16)(oacc[qi][di][r] * inv);
            *(f16x4_t*)&att[(base + q) * 1024 + h * 64 + di * 16 + quad * 4] = o;
        }
    }
}

// ---------------------------------------------------------------------------
extern "C" void kernel_launch(void* const* d_in, const int* in_sizes, int n_in,
                              void* d_out, int out_size, void* d_ws, size_t ws_size,
                              hipStream_t stream) {
    const float* x     = (const float*)d_in[0];   // [4,2048,1024]
    const int*   mask  = (const int*)d_in[1];     // [4,1,1,2048]
    const float* qkv_w = (const float*)d_in[2];   // [3072,1024]
    const float* qkv_b = (const float*)d_in[3];   // [3072]
    const float* out_w = (const float*)d_in[4];   // [1024,1024]
    const float* out_b = (const float*)d_in[5];   // [1024]
    float* out = (float*)d_out;                   // [4,2048,1024] fp32

    const int B = 4, T = 2048;
    const int M = B * T;                          // 8192
    char* ws = (char*)d_ws;                       // 64 MiB total
    f16* q_g = (f16*)(ws);                        // 16.78 MB [b,h,t,d] (pre-scaled)
    f16* k_g = (f16*)(ws + 16777216);             // 16.78 MB [b,h,ct,d] compacted
    f16* vt  = (f16*)(ws + 33554432);             // 16.78 MB [b,h,d,ct] compacted
    f16* att = (f16*)(ws + 50331648);             // 16.78 MB [t][1024]

    // d_out scratch (33.5 MB): x16 | w16 | cpos | nkv. All dead before gemm2
    // writes out. ow16 goes in q_g's region (dead after attn).
    f16* x16 = (f16*)d_out;                       // 16.78 MB
    f16* w16 = (f16*)((char*)d_out + 16777216);   //  6.29 MB
    int* cpos = (int*)((char*)d_out + 23068672);  // 32 KB
    int* nkv  = cpos + 4 * 2048;                  // 16 B
    f16* ow16 = q_g;                              //  2.10 MB (after attn)

    dim3 blk(256);
    cvt_f32_f16<<<dim3(2048), blk, 0, stream>>>(x, x16, M * 1024 / 8);
    cvt_f32_f16<<<dim3(1024), blk, 0, stream>>>(qkv_w, w16, 3072 * 1024 / 8);
    scan_mask<<<dim3(4), dim3(64), 0, stream>>>(mask, cpos, nkv);
    fill_tail<<<dim3(4, 16), blk, 0, stream>>>(nkv, k_g, vt);
    gemm_qkv_f16<<<dim3(3072 / 128, M / 128), blk, 0, stream>>>(x16, w16, qkv_b, cpos, q_g, k_g, vt, M, 1024);
    attn_f16<<<dim3(B * 16 * 16), blk, 0, stream>>>(q_g, k_g, vt, nkv, att, B, T);
    cvt_f32_f16<<<dim3(512), blk, 0, stream>>>(out_w, ow16, 1024 * 1024 / 8);
    gemm2_f16<<<dim3(1024 / 128, M / 128), blk, 0, stream>>>(att, ow16, out_b, out, M, 1024, 1024);
}

// Round 6
// 272.401 us; speedup vs baseline: 1.3658x; 1.0259x over previous
//
#include <hip/hip_runtime.h>
#include <hip/hip_bf16.h>

// fp32 in / fp32 out. Internals: single-pass fp16 MFMA.
// Round 6: compact BEFORE the QKV GEMM + launch fusion (8 -> 5 kernels).
//  - pre_pass: x->f16, qkv_w->f16 (grid-stride) + mask scan emitting
//    gpos[b][ci]=t (valid-key list) + nkv, all in one launch.
//  - gemm_qkv (blockIdx.z): z=0 Q over all 8192 rows; z=1 K/V over
//    COMPACTED rows only (~50%): per-thread A-row addrs gathered via gpos
//    ONCE before the K-loop (gload_lds global src is per-lane). Epilogue is
//    direct (no cpos scatter); V^T writes become contiguous f16x4.
//    Tail rows (ct>=nkv) stage t=0 -> finite K/V, gated by attn's rem mask
//    -> fill_tail kernel deleted.
//  - attn + gemm2 verbatim from round 5 (passing; bank-conflict 0).
// FLOPs: QKV 51.5 -> ~35.5 GF. Error budget unchanged (absmax 2e-3, thr 8e-3).
typedef _Float16 f16;
typedef _Float16 f16x4_t __attribute__((ext_vector_type(4)));
typedef _Float16 f16x8 __attribute__((ext_vector_type(8)));
typedef float f32x4 __attribute__((ext_vector_type(4)));

#define AS1(p) ((const __attribute__((address_space(1))) void*)(p))
#define AS3(p) ((__attribute__((address_space(3))) void*)(p))

__device__ __forceinline__ void gload_lds16(const f16* g, f16* l) {
    __builtin_amdgcn_global_load_lds(AS1(g), AS3(l), 16, 0, 0);
}

__device__ __forceinline__ f16x8 cvt8(float4 u, float4 v) {
    f16x8 r;
    r[0] = (f16)u.x; r[1] = (f16)u.y; r[2] = (f16)u.z; r[3] = (f16)u.w;
    r[4] = (f16)v.x; r[5] = (f16)v.y; r[6] = (f16)v.z; r[7] = (f16)v.w;
    return r;
}

// q pre-scale: 1/sqrt(64) * log2(e) so softmax is exp2(s)
#define Q_SCALE 0.180336880111f

// ---------------------------------------------------------------------------
// pre_pass: blocks 0..2047 grid-stride cvt x->x16, qkv_w->w16;
//           blocks 2048..2051 per-batch mask scan -> gpos (valid t list), nkv.
// ---------------------------------------------------------------------------
__global__ __launch_bounds__(256) void pre_pass(
    const float* __restrict__ x, const float* __restrict__ qw,
    const int* __restrict__ mask, f16* __restrict__ x16,
    f16* __restrict__ w16, int* __restrict__ gpos, int* __restrict__ nkv)
{
    const int blk = blockIdx.x;
    if (blk >= 2048) {                 // scan: wave 0 of blocks 2048..2051
        const int b = blk - 2048;
        if (threadIdx.x < 64) {
            const int lane = threadIdx.x;
            const int* mb = mask + b * 2048;
            int run = 0;
            for (int c = 0; c < 2048; c += 64) {
                int v = (mb[c + lane] != 0) ? 1 : 0;
                unsigned long long bits = __ballot(v);
                int pre = __popcll(bits & ((1ull << lane) - 1ull));
                if (v) gpos[b * 2048 + run + pre] = c + lane;
                run += __popcll(bits);
            }
            if (lane == 0) nkv[b] = run;
        }
        return;
    }
    const int nx8 = 8192 * 1024 / 8;   // 1,048,576 groups of 8
    const int nw8 = 3072 * 1024 / 8;   //   393,216
    int idx = blk * 256 + threadIdx.x;
    const int stride = 2048 * 256;
    for (int i = idx; i < nx8 + nw8; i += stride) {
        const float* s; f16* d;
        if (i < nx8) { size_t o = (size_t)i * 8;          s = x  + o; d = x16 + o; }
        else         { size_t o = (size_t)(i - nx8) * 8;  s = qw + o; d = w16 + o; }
        float4 u = *(const float4*)s;
        float4 v = *(const float4*)(s + 4);
        *(f16x8*)d = cvt8(u, v);
    }
}

// ---------------------------------------------------------------------------
// cvt_f32_f16: vectorized fp32 -> fp16 (used for out_w after attn).
// ---------------------------------------------------------------------------
__global__ __launch_bounds__(256) void cvt_f32_f16(
    const float* __restrict__ src, f16* __restrict__ dst, int n8)
{
    int idx = blockIdx.x * 256 + threadIdx.x;
    int stride = gridDim.x * 256;
    for (int i = idx; i < n8; i += stride) {
        size_t o = (size_t)i * 8;
        float4 u = *(const float4*)&src[o];
        float4 v = *(const float4*)&src[o + 4];
        *(f16x8*)&dst[o] = cvt8(u, v);
    }
}

// ---------------------------------------------------------------------------
// gemm_qkv: z=0: q = x @ wq^T (+b, *Q_SCALE) over all rows, grid x<8.
//           z=1: k,v over COMPACTED rows (A gathered via gpos), grid x<16.
// 128x128 tile, BK=64, global_load_lds + XOR involution (conflict-free).
// ---------------------------------------------------------------------------
__global__ __launch_bounds__(256) void gemm_qkv_f16(
    const f16* __restrict__ x16, const f16* __restrict__ w16,
    const float* __restrict__ bias, const int* __restrict__ gpos,
    const int* __restrict__ nkv, f16* __restrict__ q_g,
    f16* __restrict__ k_g, f16* __restrict__ vt_g)
{
    constexpr int BK = 64, K = 1024;
    __shared__ f16 As[128 * BK], Bs[128 * BK];   // 16 KB each

    const int tid  = threadIdx.x;
    const int lane = tid & 63, wave = tid >> 6;
    const int wy = wave >> 1, wx = wave & 1;
    const int lrow = lane & 15, quad = lane >> 4;
    const int srow = lane >> 3;       // row within 8-row DMA group
    const int sgrp = lane & 7;        // LDS 16B-group
    const int x0 = ((quad)     ^ (lrow & 7)) * 8;
    const int x1 = ((4 + quad) ^ (lrow & 7)) * 8;

    const int z  = blockIdx.z;
    const int bx = blockIdx.x, by = blockIdx.y;
    int b_kv = 0, mt = 0, nk = 0, nbase, n0;
    if (z == 0) {
        if (bx >= 8) return;
        nbase = 0; n0 = bx * 128;
    } else {
        b_kv = by >> 4; mt = by & 15;
        nk = nkv[b_kv];
        if (mt * 128 >= nk) return;
        nbase = 1024; n0 = bx * 128;
    }

    // per-thread staged-row base addrs, fixed across the whole K-loop
    const f16* arow[4];
    const f16* brow[4];
#pragma unroll
    for (int j = 0; j < 4; ++j) {
        int rit = (wave * 4 + j) * 8 + srow;     // row in tile [0,128)
        int trow;
        if (z == 0) {
            trow = by * 128 + rit;               // global row [0,8192)
        } else {
            int ct = mt * 128 + rit;
            int t = (ct < nk) ? gpos[b_kv * 2048 + ct] : 0;  // tail -> t=0 (finite)
            trow = b_kv * 2048 + t;
        }
        arow[j] = x16 + (size_t)trow * K + (sgrp ^ srow) * 8;
        brow[j] = w16 + (size_t)(nbase + n0 + rit) * K + (sgrp ^ srow) * 8;
    }

    f32x4 acc[4][4] = {};

    for (int k0 = 0; k0 < K; k0 += BK) {
        __syncthreads();               // all waves done reading prev tile
#pragma unroll
        for (int j = 0; j < 4; ++j) {
            int rg = wave * 4 + j;
            gload_lds16(arow[j] + k0, &As[rg * 512 + lane * 8]);
            gload_lds16(brow[j] + k0, &Bs[rg * 512 + lane * 8]);
        }
        __syncthreads();               // drains vmcnt: tile staged

        f16x8 a0[4], a1[4], b0[4], b1[4];
#pragma unroll
        for (int i = 0; i < 4; ++i) {
            const int r = (wy * 64 + i * 16 + lrow) * BK;
            a0[i] = *(const f16x8*)&As[r + x0];
            a1[i] = *(const f16x8*)&As[r + x1];
        }
#pragma unroll
        for (int j = 0; j < 4; ++j) {
            const int r = (wx * 64 + j * 16 + lrow) * BK;
            b0[j] = *(const f16x8*)&Bs[r + x0];
            b1[j] = *(const f16x8*)&Bs[r + x1];
        }
#pragma unroll
        for (int i = 0; i < 4; ++i)
#pragma unroll
            for (int j = 0; j < 4; ++j) {
                acc[i][j] = __builtin_amdgcn_mfma_f32_16x16x32_f16(a0[i], b0[j], acc[i][j], 0, 0, 0);
                acc[i][j] = __builtin_amdgcn_mfma_f32_16x16x32_f16(a1[i], b1[j], acc[i][j], 0, 0, 0);
            }
    }

    // epilogue: C/D layout col=lane&15, row=quad*4+reg
    if (z == 0) {
#pragma unroll
        for (int i = 0; i < 4; ++i) {
            size_t row = (size_t)by * 128 + wy * 64 + i * 16 + quad * 4;
            int b = (int)(row >> 11);
            int t = (int)(row & 2047);
#pragma unroll
            for (int j = 0; j < 4; ++j) {
                int col = n0 + wx * 64 + j * 16 + lrow;
                float bb = bias[col];
                int hh = col >> 6, d = col & 63;
                size_t o = ((size_t)(b * 16 + hh) * 2048 + t) * 64 + d;
#pragma unroll
                for (int r = 0; r < 4; ++r)
                    q_g[o + (size_t)r * 64] = (f16)((acc[i][j][r] + bb) * Q_SCALE);
            }
        }
    } else {
        const int region = n0 >> 10;   // 0=k, 1=v (block-uniform)
#pragma unroll
        for (int i = 0; i < 4; ++i) {
            int ct = mt * 128 + wy * 64 + i * 16 + quad * 4;
#pragma unroll
            for (int j = 0; j < 4; ++j) {
                int col = n0 + wx * 64 + j * 16 + lrow;       // [0,2048)
                float bb = bias[1024 + col];
                int cl = col & 1023, hh = cl >> 6, d = cl & 63;
                size_t bh = (size_t)(b_kv * 16 + hh);
                if (region == 0) {
#pragma unroll
                    for (int r = 0; r < 4; ++r)
                        k_g[(bh * 2048 + ct + r) * 64 + d] = (f16)(acc[i][j][r] + bb);
                } else {
                    f16x4_t pv;
#pragma unroll
                    for (int r = 0; r < 4; ++r) pv[r] = (f16)(acc[i][j][r] + bb);
                    *(f16x4_t*)&vt_g[(bh * 64 + d) * 2048 + ct] = pv;
                }
            }
        }
    }
}

// ---------------------------------------------------------------------------
// GEMM2: out = att @ ow16^T + b (all-f16 inputs, fp32 out). Verbatim round 5.
// ---------------------------------------------------------------------------
__global__ __launch_bounds__(256) void gemm2_f16(
    const f16* __restrict__ A16, const f16* __restrict__ Bw16,
    const float* __restrict__ bias, float* __restrict__ C,
    int M, int N, int K)
{
    constexpr int BK = 64;
    __shared__ f16 As[128 * BK], Bs[128 * BK];

    const int tid  = threadIdx.x;
    const int lane = tid & 63, wave = tid >> 6;
    const int wy = wave >> 1, wx = wave & 1;
    const int lrow = lane & 15, quad = lane >> 4;
    const size_t m0 = (size_t)blockIdx.y * 128;
    const size_t n0 = (size_t)blockIdx.x * 128;
    const int srow = lane >> 3, sgrp = lane & 7;
    const int x0 = ((quad)     ^ (lrow & 7)) * 8;
    const int x1 = ((4 + quad) ^ (lrow & 7)) * 8;

    f32x4 acc[4][4] = {};

    for (int k0 = 0; k0 < K; k0 += BK) {
        __syncthreads();
#pragma unroll
        for (int j = 0; j < 4; ++j) {
            int rg  = wave * 4 + j;
            int row = rg * 8 + srow;
            int grp = sgrp ^ srow;
            gload_lds16(&A16[(m0 + row) * (size_t)K + k0 + grp * 8],
                        &As[rg * 512 + lane * 8]);
            gload_lds16(&Bw16[(n0 + row) * (size_t)K + k0 + grp * 8],
                        &Bs[rg * 512 + lane * 8]);
        }
        __syncthreads();

        f16x8 a0[4], a1[4], b0[4], b1[4];
#pragma unroll
        for (int i = 0; i < 4; ++i) {
            const int r = (wy * 64 + i * 16 + lrow) * BK;
            a0[i] = *(const f16x8*)&As[r + x0];
            a1[i] = *(const f16x8*)&As[r + x1];
        }
#pragma unroll
        for (int j = 0; j < 4; ++j) {
            const int r = (wx * 64 + j * 16 + lrow) * BK;
            b0[j] = *(const f16x8*)&Bs[r + x0];
            b1[j] = *(const f16x8*)&Bs[r + x1];
        }
#pragma unroll
        for (int i = 0; i < 4; ++i)
#pragma unroll
            for (int j = 0; j < 4; ++j) {
                acc[i][j] = __builtin_amdgcn_mfma_f32_16x16x32_f16(a0[i], b0[j], acc[i][j], 0, 0, 0);
                acc[i][j] = __builtin_amdgcn_mfma_f32_16x16x32_f16(a1[i], b1[j], acc[i][j], 0, 0, 0);
            }
    }

#pragma unroll
    for (int i = 0; i < 4; ++i) {
        size_t row = m0 + wy * 64 + i * 16 + quad * 4;
#pragma unroll
        for (int j = 0; j < 4; ++j) {
            size_t col = n0 + wx * 64 + j * 16 + lrow;
            float bb = bias[col];
#pragma unroll
            for (int r = 0; r < 4; ++r)
                C[(row + r) * N + col] = acc[i][j][r] + bb;
        }
    }
}

// ---------------------------------------------------------------------------
// Attention over COMPACTED keys (verbatim round 5 - passing). Tail keys
// [nkv, pad64) now hold finite garbage (t=0 projections) - gated by rem.
// ---------------------------------------------------------------------------
__global__ __launch_bounds__(256) void attn_f16(
    const f16* __restrict__ q_g, const f16* __restrict__ k_g,
    const f16* __restrict__ vt_g, const int* __restrict__ nkv,
    f16* __restrict__ att, int B, int T)
{
    constexpr int LDP = 72;
    __shared__ f16 Ks_s[2][64 * 64];
    __shared__ f16 Vt_s[2][64 * 64];
    __shared__ f16 Pt[128 * LDP];

    const int tid  = threadIdx.x;
    const int lane = tid & 63, wave = tid >> 6;
    const int lrow = lane & 15, quad = lane >> 4;
    const int bid = ((int)blockIdx.x & 7) * 128 + ((int)blockIdx.x >> 3);
    const int qt = bid & 15;
    const int h  = (bid >> 4) & 15;
    const int b  = bid >> 8;
    const size_t base = (size_t)b * T;
    const size_t bh = (size_t)(b * 16 + h);
    const f16* qg_base = q_g  + bh * (2048 * 64);
    const f16* kg_base = k_g  + bh * (2048 * 64);
    const f16* vt_base = vt_g + bh * (64 * 2048);

    const int nk = nkv[b];
    const int ntiles = (nk + 63) >> 6;

    const int x0 = ((quad)     ^ (lrow & 7)) * 8;
    const int x1 = ((4 + quad) ^ (lrow & 7)) * 8;

    f16x8 aq[2][2];
#pragma unroll
    for (int qi = 0; qi < 2; ++qi)
#pragma unroll
        for (int ks = 0; ks < 2; ++ks)
            aq[qi][ks] = *(const f16x8*)&qg_base[
                (size_t)(qt * 128 + wave * 32 + qi * 16 + lrow) * 64 + ks * 32 + quad * 8];

    f32x4 oacc[2][4] = {};
    float l_part[2] = {0.f, 0.f};

    const int srow0 = (lane >> 3);
    const int sgrp  = (lane & 7);

    auto stage = [&](int kt, int bsel) {
        const f16* kT = kg_base + kt * 4096;
#pragma unroll
        for (int j = 0; j < 2; ++j) {
            int rg  = wave + j * 4;
            int row = rg * 8 + srow0;
            int grp = sgrp ^ (row & 7);
            gload_lds16(&kT[row * 64 + grp * 8], &Ks_s[bsel][rg * 512 + lane * 8]);
            gload_lds16(&vt_base[(size_t)row * 2048 + kt * 64 + grp * 8],
                        &Vt_s[bsel][rg * 512 + lane * 8]);
        }
    };

    stage(0, 0);
    __syncthreads();

    for (int kt = 0; kt < ntiles; ++kt) {
        const int cur = kt & 1;
        if (kt + 1 < ntiles) stage(kt + 1, cur ^ 1);

        const f16* Ks = Ks_s[cur];
        const f16* Vt = Vt_s[cur];

        f32x4 s[2][4];
        __builtin_amdgcn_s_setprio(1);
#pragma unroll
        for (int ni = 0; ni < 4; ++ni) {
            const int key = ni * 16 + lrow;
            f16x8 k0 = *(const f16x8*)&Ks[key * 64 + x0];
            f16x8 k1 = *(const f16x8*)&Ks[key * 64 + x1];
#pragma unroll
            for (int qi = 0; qi < 2; ++qi) {
                f32x4 t = {0.f, 0.f, 0.f, 0.f};
                t = __builtin_amdgcn_mfma_f32_16x16x32_f16(k0, aq[qi][0], t, 0, 0, 0);
                t = __builtin_amdgcn_mfma_f32_16x16x32_f16(k1, aq[qi][1], t, 0, 0, 0);
                s[qi][ni] = t;
            }
        }
        __builtin_amdgcn_s_setprio(0);

        const int rem = nk - kt * 64;
        auto softmax = [&](bool masked) {
#pragma unroll
            for (int qi = 0; qi < 2; ++qi)
#pragma unroll
                for (int ni = 0; ni < 4; ++ni) {
                    float p[4];
#pragma unroll
                    for (int r = 0; r < 4; ++r) {
                        float e = __builtin_amdgcn_exp2f(s[qi][ni][r]);
                        p[r] = (!masked || (ni * 16 + quad * 4 + r) < rem) ? e : 0.f;
                    }
                    l_part[qi] += (p[0] + p[1]) + (p[2] + p[3]);
                    f16x4_t pk;
#pragma unroll
                    for (int r = 0; r < 4; ++r) pk[r] = (f16)p[r];
                    *(f16x4_t*)&Pt[(wave * 32 + qi * 16 + lrow) * LDP + ni * 16 + quad * 4] = pk;
                }
        };
        if (rem >= 64) softmax(false); else softmax(true);

        f16x8 pf[2][2];
#pragma unroll
        for (int qi = 0; qi < 2; ++qi)
#pragma unroll
            for (int ks = 0; ks < 2; ++ks)
                pf[qi][ks] = *(const f16x8*)&Pt[(wave * 32 + qi * 16 + lrow) * LDP + ks * 32 + quad * 8];
        __builtin_amdgcn_s_setprio(1);
#pragma unroll
        for (int di = 0; di < 4; ++di) {
            const int d = di * 16 + lrow;
            f16x8 v0 = *(const f16x8*)&Vt[d * 64 + x0];
            f16x8 v1 = *(const f16x8*)&Vt[d * 64 + x1];
#pragma unroll
            for (int qi = 0; qi < 2; ++qi) {
                oacc[qi][di] = __builtin_amdgcn_mfma_f32_16x16x32_f16(v0, pf[qi][0], oacc[qi][di], 0, 0, 0);
                oacc[qi][di] = __builtin_amdgcn_mfma_f32_16x16x32_f16(v1, pf[qi][1], oacc[qi][di], 0, 0, 0);
            }
        }
        __builtin_amdgcn_s_setprio(0);

        __syncthreads();
    }

#pragma unroll
    for (int qi = 0; qi < 2; ++qi) {
        float v = l_part[qi];
        v += __shfl_xor(v, 16);
        v += __shfl_xor(v, 32);
        float inv = 1.f / v;
        int q = qt * 128 + wave * 32 + qi * 16 + lrow;
#pragma unroll
        for (int di = 0; di < 4; ++di) {
            f16x4_t o;
#pragma unroll
            for (int r = 0; r < 4; ++r) o[r] = (f16)(oacc[qi][di][r] * inv);
            *(f16x4_t*)&att[(base + q) * 1024 + h * 64 + di * 16 + quad * 4] = o;
        }
    }
}

// ---------------------------------------------------------------------------
extern "C" void kernel_launch(void* const* d_in, const int* in_sizes, int n_in,
                              void* d_out, int out_size, void* d_ws, size_t ws_size,
                              hipStream_t stream) {
    const float* x     = (const float*)d_in[0];   // [4,2048,1024]
    const int*   mask  = (const int*)d_in[1];     // [4,1,1,2048]
    const float* qkv_w = (const float*)d_in[2];   // [3072,1024]
    const float* qkv_b = (const float*)d_in[3];   // [3072]
    const float* out_w = (const float*)d_in[4];   // [1024,1024]
    const float* out_b = (const float*)d_in[5];   // [1024]
    float* out = (float*)d_out;                   // [4,2048,1024] fp32

    const int B = 4, T = 2048;
    const int M = B * T;                          // 8192
    char* ws = (char*)d_ws;
    f16* q_g = (f16*)(ws);                        // 16.78 MB [b,h,t,d] (pre-scaled)
    f16* k_g = (f16*)(ws + 16777216);             // 16.78 MB [b,h,ct,d] compacted
    f16* vt  = (f16*)(ws + 33554432);             // 16.78 MB [b,h,d,ct] compacted
    f16* att = (f16*)(ws + 50331648);             // 16.78 MB [t][1024]

    // d_out scratch (33.5 MB): x16 | w16 | gpos | nkv. All dead before gemm2
    // writes out. ow16 goes in q_g region (dead after attn).
    f16* x16 = (f16*)d_out;                       // 16.78 MB
    f16* w16 = (f16*)((char*)d_out + 16777216);   //  6.29 MB
    int* gpos = (int*)((char*)d_out + 23068672);  // 32 KB
    int* nkv  = gpos + 4 * 2048;                  // 16 B
    f16* ow16 = q_g;                              //  2.10 MB (after attn)

    dim3 blk(256);
    pre_pass<<<dim3(2052), blk, 0, stream>>>(x, qkv_w, mask, x16, w16, gpos, nkv);
    gemm_qkv_f16<<<dim3(16, 64, 2), blk, 0, stream>>>(x16, w16, qkv_b, gpos, nkv, q_g, k_g, vt);
    attn_f16<<<dim3(B * 16 * 16), blk, 0, stream>>>(q_g, k_g, vt, nkv, att, B, T);
    cvt_f32_f16<<<dim3(512), blk, 0, stream>>>(out_w, ow16, 1024 * 1024 / 8);
    gemm2_f16<<<dim3(1024 / 128, M / 128), blk, 0, stream>>>(att, ow16, out_b, out, M, 1024, 1024);
}

// Round 7
// 255.503 us; speedup vs baseline: 1.4561x; 1.0661x over previous
//
#include <hip/hip_runtime.h>
#include <hip/hip_bf16.h>

// fp32 in / fp32 out. Internals: single-pass fp16 MFMA.
// Round 7: double-buffered single-barrier K-loop for BOTH GEMMs (the exact
// staging pipeline the attn kernel already uses, measured+passing):
//   stage(kt+1) -> alt buffer BEFORE compute(kt); ONE __syncthreads per iter
//   (drains vmcnt for next tile AND protects cur buffer). Round-6 counters
//   (MfmaUtil 17%, VALUBusy 14%, Occ 11%) showed the 2-barrier loop exposing
//   full staging latency every iteration.
// Also: merged QKV grid (24,64) - no always-dead blocks (was 2048 blocks
// with ~1024 dead; round-6 Occupancy 11%).
// Kept verbatim: pre_pass (cvt+scan), compact-before-GEMM gather, attn,
// cvt(out_w). Error budget unchanged (absmax 2e-3, thr 8e-3).
typedef _Float16 f16;
typedef _Float16 f16x4_t __attribute__((ext_vector_type(4)));
typedef _Float16 f16x8 __attribute__((ext_vector_type(8)));
typedef float f32x4 __attribute__((ext_vector_type(4)));

#define AS1(p) ((const __attribute__((address_space(1))) void*)(p))
#define AS3(p) ((__attribute__((address_space(3))) void*)(p))

__device__ __forceinline__ void gload_lds16(const f16* g, f16* l) {
    __builtin_amdgcn_global_load_lds(AS1(g), AS3(l), 16, 0, 0);
}

__device__ __forceinline__ f16x8 cvt8(float4 u, float4 v) {
    f16x8 r;
    r[0] = (f16)u.x; r[1] = (f16)u.y; r[2] = (f16)u.z; r[3] = (f16)u.w;
    r[4] = (f16)v.x; r[5] = (f16)v.y; r[6] = (f16)v.z; r[7] = (f16)v.w;
    return r;
}

// q pre-scale: 1/sqrt(64) * log2(e) so softmax is exp2(s)
#define Q_SCALE 0.180336880111f

// ---------------------------------------------------------------------------
// pre_pass: blocks 0..2047 grid-stride cvt x->x16, qkv_w->w16;
//           blocks 2048..2051 per-batch mask scan -> gpos (valid t list), nkv.
// ---------------------------------------------------------------------------
__global__ __launch_bounds__(256) void pre_pass(
    const float* __restrict__ x, const float* __restrict__ qw,
    const int* __restrict__ mask, f16* __restrict__ x16,
    f16* __restrict__ w16, int* __restrict__ gpos, int* __restrict__ nkv)
{
    const int blk = blockIdx.x;
    if (blk >= 2048) {                 // scan: wave 0 of blocks 2048..2051
        const int b = blk - 2048;
        if (threadIdx.x < 64) {
            const int lane = threadIdx.x;
            const int* mb = mask + b * 2048;
            int run = 0;
            for (int c = 0; c < 2048; c += 64) {
                int v = (mb[c + lane] != 0) ? 1 : 0;
                unsigned long long bits = __ballot(v);
                int pre = __popcll(bits & ((1ull << lane) - 1ull));
                if (v) gpos[b * 2048 + run + pre] = c + lane;
                run += __popcll(bits);
            }
            if (lane == 0) nkv[b] = run;
        }
        return;
    }
    const int nx8 = 8192 * 1024 / 8;   // 1,048,576 groups of 8
    const int nw8 = 3072 * 1024 / 8;   //   393,216
    int idx = blk * 256 + threadIdx.x;
    const int stride = 2048 * 256;
    for (int i = idx; i < nx8 + nw8; i += stride) {
        const float* s; f16* d;
        if (i < nx8) { size_t o = (size_t)i * 8;          s = x  + o; d = x16 + o; }
        else         { size_t o = (size_t)(i - nx8) * 8;  s = qw + o; d = w16 + o; }
        float4 u = *(const float4*)s;
        float4 v = *(const float4*)(s + 4);
        *(f16x8*)d = cvt8(u, v);
    }
}

// ---------------------------------------------------------------------------
// cvt_f32_f16: vectorized fp32 -> fp16 (used for out_w after attn).
// ---------------------------------------------------------------------------
__global__ __launch_bounds__(256) void cvt_f32_f16(
    const float* __restrict__ src, f16* __restrict__ dst, int n8)
{
    int idx = blockIdx.x * 256 + threadIdx.x;
    int stride = gridDim.x * 256;
    for (int i = idx; i < n8; i += stride) {
        size_t o = (size_t)i * 8;
        float4 u = *(const float4*)&src[o];
        float4 v = *(const float4*)&src[o + 4];
        *(f16x8*)&dst[o] = cvt8(u, v);
    }
}

// ---------------------------------------------------------------------------
// gemm_qkv: grid (24,64). bx<8: Q over all rows (n0=bx*128, m-tile=by).
//           bx>=8: K/V over COMPACTED rows (gathered via gpos; n0=(bx-8)*128,
//           by -> b_kv=by>>4, mt=by&15; tail blocks exit).
// 128x128 tile, BK=64, DOUBLE-BUFFERED global_load_lds (1 barrier/iter),
// XOR involution (conflict-free).
// ---------------------------------------------------------------------------
__global__ __launch_bounds__(256) void gemm_qkv_f16(
    const f16* __restrict__ x16, const f16* __restrict__ w16,
    const float* __restrict__ bias, const int* __restrict__ gpos,
    const int* __restrict__ nkv, f16* __restrict__ q_g,
    f16* __restrict__ k_g, f16* __restrict__ vt_g)
{
    constexpr int BK = 64, K = 1024, NT = K / BK;
    __shared__ f16 As[2][128 * BK], Bs[2][128 * BK];   // 64 KB total

    const int tid  = threadIdx.x;
    const int lane = tid & 63, wave = tid >> 6;
    const int wy = wave >> 1, wx = wave & 1;
    const int lrow = lane & 15, quad = lane >> 4;
    const int srow = lane >> 3;       // row within 8-row DMA group
    const int sgrp = lane & 7;        // LDS 16B-group
    const int x0 = ((quad)     ^ (lrow & 7)) * 8;
    const int x1 = ((4 + quad) ^ (lrow & 7)) * 8;

    const int bx = blockIdx.x, by = blockIdx.y;
    const int z = (bx >= 8);
    int b_kv = 0, mt = 0, nk = 0, nbase, n0;
    if (!z) {
        nbase = 0; n0 = bx * 128;
    } else {
        b_kv = by >> 4; mt = by & 15;
        nk = nkv[b_kv];
        if (mt * 128 >= nk) return;
        nbase = 1024; n0 = (bx - 8) * 128;
    }

    // per-thread staged-row base addrs, fixed across the whole K-loop
    const f16* arow[4];
    const f16* brow[4];
#pragma unroll
    for (int j = 0; j < 4; ++j) {
        int rit = (wave * 4 + j) * 8 + srow;     // row in tile [0,128)
        int trow;
        if (!z) {
            trow = by * 128 + rit;               // global row [0,8192)
        } else {
            int ct = mt * 128 + rit;
            int t = (ct < nk) ? gpos[b_kv * 2048 + ct] : 0;  // tail -> t=0 (finite)
            trow = b_kv * 2048 + t;
        }
        arow[j] = x16 + (size_t)trow * K + (sgrp ^ srow) * 8;
        brow[j] = w16 + (size_t)(nbase + n0 + rit) * K + (sgrp ^ srow) * 8;
    }

    auto stage = [&](int k0, int bsel) {
#pragma unroll
        for (int j = 0; j < 4; ++j) {
            int rg = wave * 4 + j;
            gload_lds16(arow[j] + k0, &As[bsel][rg * 512 + lane * 8]);
            gload_lds16(brow[j] + k0, &Bs[bsel][rg * 512 + lane * 8]);
        }
    };

    f32x4 acc[4][4] = {};

    stage(0, 0);
    __syncthreads();                   // tile 0 staged

    for (int kt = 0; kt < NT; ++kt) {
        const int cur = kt & 1;
        // issue next-tile stage FIRST: latency hides under this tile's MFMAs
        if (kt + 1 < NT) stage((kt + 1) * BK, cur ^ 1);

        f16x8 a0[4], a1[4], b0[4], b1[4];
#pragma unroll
        for (int i = 0; i < 4; ++i) {
            const int r = (wy * 64 + i * 16 + lrow) * BK;
            a0[i] = *(const f16x8*)&As[cur][r + x0];
            a1[i] = *(const f16x8*)&As[cur][r + x1];
        }
#pragma unroll
        for (int j = 0; j < 4; ++j) {
            const int r = (wx * 64 + j * 16 + lrow) * BK;
            b0[j] = *(const f16x8*)&Bs[cur][r + x0];
            b1[j] = *(const f16x8*)&Bs[cur][r + x1];
        }
        __builtin_amdgcn_s_setprio(1);
#pragma unroll
        for (int i = 0; i < 4; ++i)
#pragma unroll
            for (int j = 0; j < 4; ++j) {
                acc[i][j] = __builtin_amdgcn_mfma_f32_16x16x32_f16(a0[i], b0[j], acc[i][j], 0, 0, 0);
                acc[i][j] = __builtin_amdgcn_mfma_f32_16x16x32_f16(a1[i], b1[j], acc[i][j], 0, 0, 0);
            }
        __builtin_amdgcn_s_setprio(0);

        // single barrier: drains next-tile loads AND protects cur buffer
        __syncthreads();
    }

    // epilogue: C/D layout col=lane&15, row=quad*4+reg
    if (!z) {
#pragma unroll
        for (int i = 0; i < 4; ++i) {
            size_t row = (size_t)by * 128 + wy * 64 + i * 16 + quad * 4;
            int b = (int)(row >> 11);
            int t = (int)(row & 2047);
#pragma unroll
            for (int j = 0; j < 4; ++j) {
                int col = n0 + wx * 64 + j * 16 + lrow;
                float bb = bias[col];
                int hh = col >> 6, d = col & 63;
                size_t o = ((size_t)(b * 16 + hh) * 2048 + t) * 64 + d;
#pragma unroll
                for (int r = 0; r < 4; ++r)
                    q_g[o + (size_t)r * 64] = (f16)((acc[i][j][r] + bb) * Q_SCALE);
            }
        }
    } else {
        const int region = n0 >> 10;   // 0=k, 1=v (block-uniform)
#pragma unroll
        for (int i = 0; i < 4; ++i) {
            int ct = mt * 128 + wy * 64 + i * 16 + quad * 4;
#pragma unroll
            for (int j = 0; j < 4; ++j) {
                int col = n0 + wx * 64 + j * 16 + lrow;       // [0,2048)
                float bb = bias[1024 + col];
                int cl = col & 1023, hh = cl >> 6, d = cl & 63;
                size_t bh = (size_t)(b_kv * 16 + hh);
                if (region == 0) {
#pragma unroll
                    for (int r = 0; r < 4; ++r)
                        k_g[(bh * 2048 + ct + r) * 64 + d] = (f16)(acc[i][j][r] + bb);
                } else {
                    f16x4_t pv;
#pragma unroll
                    for (int r = 0; r < 4; ++r) pv[r] = (f16)(acc[i][j][r] + bb);
                    *(f16x4_t*)&vt_g[(bh * 64 + d) * 2048 + ct] = pv;
                }
            }
        }
    }
}

// ---------------------------------------------------------------------------
// GEMM2: out = att @ ow16^T + b. Same dbuf single-barrier pipeline.
// ---------------------------------------------------------------------------
__global__ __launch_bounds__(256) void gemm2_f16(
    const f16* __restrict__ A16, const f16* __restrict__ Bw16,
    const float* __restrict__ bias, float* __restrict__ C,
    int M, int N, int K)
{
    constexpr int BK = 64;
    __shared__ f16 As[2][128 * BK], Bs[2][128 * BK];

    const int tid  = threadIdx.x;
    const int lane = tid & 63, wave = tid >> 6;
    const int wy = wave >> 1, wx = wave & 1;
    const int lrow = lane & 15, quad = lane >> 4;
    const size_t m0 = (size_t)blockIdx.y * 128;
    const size_t n0 = (size_t)blockIdx.x * 128;
    const int srow = lane >> 3, sgrp = lane & 7;
    const int x0 = ((quad)     ^ (lrow & 7)) * 8;
    const int x1 = ((4 + quad) ^ (lrow & 7)) * 8;

    const f16* arow[4];
    const f16* brow[4];
#pragma unroll
    for (int j = 0; j < 4; ++j) {
        int rit = (wave * 4 + j) * 8 + srow;
        arow[j] = A16  + (m0 + rit) * (size_t)K + (sgrp ^ srow) * 8;
        brow[j] = Bw16 + (n0 + rit) * (size_t)K + (sgrp ^ srow) * 8;
    }

    auto stage = [&](int k0, int bsel) {
#pragma unroll
        for (int j = 0; j < 4; ++j) {
            int rg = wave * 4 + j;
            gload_lds16(arow[j] + k0, &As[bsel][rg * 512 + lane * 8]);
            gload_lds16(brow[j] + k0, &Bs[bsel][rg * 512 + lane * 8]);
        }
    };

    f32x4 acc[4][4] = {};
    const int NT = K / BK;

    stage(0, 0);
    __syncthreads();

    for (int kt = 0; kt < NT; ++kt) {
        const int cur = kt & 1;
        if (kt + 1 < NT) stage((kt + 1) * BK, cur ^ 1);

        f16x8 a0[4], a1[4], b0[4], b1[4];
#pragma unroll
        for (int i = 0; i < 4; ++i) {
            const int r = (wy * 64 + i * 16 + lrow) * BK;
            a0[i] = *(const f16x8*)&As[cur][r + x0];
            a1[i] = *(const f16x8*)&As[cur][r + x1];
        }
#pragma unroll
        for (int j = 0; j < 4; ++j) {
            const int r = (wx * 64 + j * 16 + lrow) * BK;
            b0[j] = *(const f16x8*)&Bs[cur][r + x0];
            b1[j] = *(const f16x8*)&Bs[cur][r + x1];
        }
        __builtin_amdgcn_s_setprio(1);
#pragma unroll
        for (int i = 0; i < 4; ++i)
#pragma unroll
            for (int j = 0; j < 4; ++j) {
                acc[i][j] = __builtin_amdgcn_mfma_f32_16x16x32_f16(a0[i], b0[j], acc[i][j], 0, 0, 0);
                acc[i][j] = __builtin_amdgcn_mfma_f32_16x16x32_f16(a1[i], b1[j], acc[i][j], 0, 0, 0);
            }
        __builtin_amdgcn_s_setprio(0);

        __syncthreads();
    }

#pragma unroll
    for (int i = 0; i < 4; ++i) {
        size_t row = m0 + wy * 64 + i * 16 + quad * 4;
#pragma unroll
        for (int j = 0; j < 4; ++j) {
            size_t col = n0 + wx * 64 + j * 16 + lrow;
            float bb = bias[col];
#pragma unroll
            for (int r = 0; r < 4; ++r)
                C[(row + r) * N + col] = acc[i][j][r] + bb;
        }
    }
}

// ---------------------------------------------------------------------------
// Attention over COMPACTED keys (verbatim round 5/6 - passing). Tail keys
// [nkv, pad64) hold finite garbage (t=0 projections) - gated by rem.
// ---------------------------------------------------------------------------
__global__ __launch_bounds__(256) void attn_f16(
    const f16* __restrict__ q_g, const f16* __restrict__ k_g,
    const f16* __restrict__ vt_g, const int* __restrict__ nkv,
    f16* __restrict__ att, int B, int T)
{
    constexpr int LDP = 72;
    __shared__ f16 Ks_s[2][64 * 64];
    __shared__ f16 Vt_s[2][64 * 64];
    __shared__ f16 Pt[128 * LDP];

    const int tid  = threadIdx.x;
    const int lane = tid & 63, wave = tid >> 6;
    const int lrow = lane & 15, quad = lane >> 4;
    const int bid = ((int)blockIdx.x & 7) * 128 + ((int)blockIdx.x >> 3);
    const int qt = bid & 15;
    const int h  = (bid >> 4) & 15;
    const int b  = bid >> 8;
    const size_t base = (size_t)b * T;
    const size_t bh = (size_t)(b * 16 + h);
    const f16* qg_base = q_g  + bh * (2048 * 64);
    const f16* kg_base = k_g  + bh * (2048 * 64);
    const f16* vt_base = vt_g + bh * (64 * 2048);

    const int nk = nkv[b];
    const int ntiles = (nk + 63) >> 6;

    const int x0 = ((quad)     ^ (lrow & 7)) * 8;
    const int x1 = ((4 + quad) ^ (lrow & 7)) * 8;

    f16x8 aq[2][2];
#pragma unroll
    for (int qi = 0; qi < 2; ++qi)
#pragma unroll
        for (int ks = 0; ks < 2; ++ks)
            aq[qi][ks] = *(const f16x8*)&qg_base[
                (size_t)(qt * 128 + wave * 32 + qi * 16 + lrow) * 64 + ks * 32 + quad * 8];

    f32x4 oacc[2][4] = {};
    float l_part[2] = {0.f, 0.f};

    const int srow0 = (lane >> 3);
    const int sgrp  = (lane & 7);

    auto stage = [&](int kt, int bsel) {
        const f16* kT = kg_base + kt * 4096;
#pragma unroll
        for (int j = 0; j < 2; ++j) {
            int rg  = wave + j * 4;
            int row = rg * 8 + srow0;
            int grp = sgrp ^ (row & 7);
            gload_lds16(&kT[row * 64 + grp * 8], &Ks_s[bsel][rg * 512 + lane * 8]);
            gload_lds16(&vt_base[(size_t)row * 2048 + kt * 64 + grp * 8],
                        &Vt_s[bsel][rg * 512 + lane * 8]);
        }
    };

    stage(0, 0);
    __syncthreads();

    for (int kt = 0; kt < ntiles; ++kt) {
        const int cur = kt & 1;
        if (kt + 1 < ntiles) stage(kt + 1, cur ^ 1);

        const f16* Ks = Ks_s[cur];
        const f16* Vt = Vt_s[cur];

        f32x4 s[2][4];
        __builtin_amdgcn_s_setprio(1);
#pragma unroll
        for (int ni = 0; ni < 4; ++ni) {
            const int key = ni * 16 + lrow;
            f16x8 k0 = *(const f16x8*)&Ks[key * 64 + x0];
            f16x8 k1 = *(const f16x8*)&Ks[key * 64 + x1];
#pragma unroll
            for (int qi = 0; qi < 2; ++qi) {
                f32x4 t = {0.f, 0.f, 0.f, 0.f};
                t = __builtin_amdgcn_mfma_f32_16x16x32_f16(k0, aq[qi][0], t, 0, 0, 0);
                t = __builtin_amdgcn_mfma_f32_16x16x32_f16(k1, aq[qi][1], t, 0, 0, 0);
                s[qi][ni] = t;
            }
        }
        __builtin_amdgcn_s_setprio(0);

        const int rem = nk - kt * 64;
        auto softmax = [&](bool masked) {
#pragma unroll
            for (int qi = 0; qi < 2; ++qi)
#pragma unroll
                for (int ni = 0; ni < 4; ++ni) {
                    float p[4];
#pragma unroll
                    for (int r = 0; r < 4; ++r) {
                        float e = __builtin_amdgcn_exp2f(s[qi][ni][r]);
                        p[r] = (!masked || (ni * 16 + quad * 4 + r) < rem) ? e : 0.f;
                    }
                    l_part[qi] += (p[0] + p[1]) + (p[2] + p[3]);
                    f16x4_t pk;
#pragma unroll
                    for (int r = 0; r < 4; ++r) pk[r] = (f16)p[r];
                    *(f16x4_t*)&Pt[(wave * 32 + qi * 16 + lrow) * LDP + ni * 16 + quad * 4] = pk;
                }
        };
        if (rem >= 64) softmax(false); else softmax(true);

        f16x8 pf[2][2];
#pragma unroll
        for (int qi = 0; qi < 2; ++qi)
#pragma unroll
            for (int ks = 0; ks < 2; ++ks)
                pf[qi][ks] = *(const f16x8*)&Pt[(wave * 32 + qi * 16 + lrow) * LDP + ks * 32 + quad * 8];
        __builtin_amdgcn_s_setprio(1);
#pragma unroll
        for (int di = 0; di < 4; ++di) {
            const int d = di * 16 + lrow;
            f16x8 v0 = *(const f16x8*)&Vt[d * 64 + x0];
            f16x8 v1 = *(const f16x8*)&Vt[d * 64 + x1];
#pragma unroll
            for (int qi = 0; qi < 2; ++qi) {
                oacc[qi][di] = __builtin_amdgcn_mfma_f32_16x16x32_f16(v0, pf[qi][0], oacc[qi][di], 0, 0, 0);
                oacc[qi][di] = __builtin_amdgcn_mfma_f32_16x16x32_f16(v1, pf[qi][1], oacc[qi][di], 0, 0, 0);
            }
        }
        __builtin_amdgcn_s_setprio(0);

        __syncthreads();
    }

#pragma unroll
    for (int qi = 0; qi < 2; ++qi) {
        float v = l_part[qi];
        v += __shfl_xor(v, 16);
        v += __shfl_xor(v, 32);
        float inv = 1.f / v;
        int q = qt * 128 + wave * 32 + qi * 16 + lrow;
#pragma unroll
        for (int di = 0; di < 4; ++di) {
            f16x4_t o;
#pragma unroll
            for (int r = 0; r < 4; ++r) o[r] = (f16)(oacc[qi][di][r] * inv);
            *(f16x4_t*)&att[(base + q) * 1024 + h * 64 + di * 16 + quad * 4] = o;
        }
    }
}

// ---------------------------------------------------------------------------
extern "C" void kernel_launch(void* const* d_in, const int* in_sizes, int n_in,
                              void* d_out, int out_size, void* d_ws, size_t ws_size,
                              hipStream_t stream) {
    const float* x     = (const float*)d_in[0];   // [4,2048,1024]
    const int*   mask  = (const int*)d_in[1];     // [4,1,1,2048]
    const float* qkv_w = (const float*)d_in[2];   // [3072,1024]
    const float* qkv_b = (const float*)d_in[3];   // [3072]
    const float* out_w = (const float*)d_in[4];   // [1024,1024]
    const float* out_b = (const float*)d_in[5];   // [1024]
    float* out = (float*)d_out;                   // [4,2048,1024] fp32

    const int B = 4, T = 2048;
    const int M = B * T;                          // 8192
    char* ws = (char*)d_ws;
    f16* q_g = (f16*)(ws);                        // 16.78 MB [b,h,t,d] (pre-scaled)
    f16* k_g = (f16*)(ws + 16777216);             // 16.78 MB [b,h,ct,d] compacted
    f16* vt  = (f16*)(ws + 33554432);             // 16.78 MB [b,h,d,ct] compacted
    f16* att = (f16*)(ws + 50331648);             // 16.78 MB [t][1024]

    // d_out scratch (33.5 MB): x16 | w16 | gpos | nkv. All dead before gemm2
    // writes out. ow16 goes in q_g region (dead after attn).
    f16* x16 = (f16*)d_out;                       // 16.78 MB
    f16* w16 = (f16*)((char*)d_out + 16777216);   //  6.29 MB
    int* gpos = (int*)((char*)d_out + 23068672);  // 32 KB
    int* nkv  = gpos + 4 * 2048;                  // 16 B
    f16* ow16 = q_g;                              //  2.10 MB (after attn)

    dim3 blk(256);
    pre_pass<<<dim3(2052), blk, 0, stream>>>(x, qkv_w, mask, x16, w16, gpos, nkv);
    gemm_qkv_f16<<<dim3(24, 64), blk, 0, stream>>>(x16, w16, qkv_b, gpos, nkv, q_g, k_g, vt);
    attn_f16<<<dim3(B * 16 * 16), blk, 0, stream>>>(q_g, k_g, vt, nkv, att, B, T);
    cvt_f32_f16<<<dim3(512), blk, 0, stream>>>(out_w, ow16, 1024 * 1024 / 8);
    gemm2_f16<<<dim3(1024 / 128, M / 128), blk, 0, stream>>>(att, ow16, out_b, out, M, 1024, 1024);
}

// Round 8
// 252.862 us; speedup vs baseline: 1.4713x; 1.0104x over previous
//
#include <hip/hip_runtime.h>
#include <hip/hip_bf16.h>

// fp32 in / fp32 out. Internals: single-pass fp16 MFMA.
// Round 8: counted-vmcnt K-loop in gemm_qkv (T4). Round-7's single
// __syncthreads/iter lowers to s_waitcnt vmcnt(0)+s_barrier = full drain of
// the prefetch issued ~300cy earlier vs ~900cy HBM latency (MfmaUtil stuck
// at 18%). New loop (raw barriers, never vmcnt(0) in steady state):
//   compute(cur) -> s_barrier(#1, readers done, NO drain)
//   -> stage(kt+2 -> cur) -> s_waitcnt vmcnt(8) (own kt+1 loads retired;
//      kt+2 flying) -> s_barrier(#2: every wave waited ITS vmcnt before the
//      barrier => tile kt+1 LDS-visible to all waves).
// vmcnt is per-wave => wait must precede barrier #2; WAR protected by #1.
// ONE sync-structure change this round; attn/gemm2/pre_pass/cvt verbatim
// from passing round 7. Error budget unchanged (absmax 2e-3, thr 8e-3).
typedef _Float16 f16;
typedef _Float16 f16x4_t __attribute__((ext_vector_type(4)));
typedef _Float16 f16x8 __attribute__((ext_vector_type(8)));
typedef float f32x4 __attribute__((ext_vector_type(4)));

#define AS1(p) ((const __attribute__((address_space(1))) void*)(p))
#define AS3(p) ((__attribute__((address_space(3))) void*)(p))

__device__ __forceinline__ void gload_lds16(const f16* g, f16* l) {
    __builtin_amdgcn_global_load_lds(AS1(g), AS3(l), 16, 0, 0);
}

__device__ __forceinline__ f16x8 cvt8(float4 u, float4 v) {
    f16x8 r;
    r[0] = (f16)u.x; r[1] = (f16)u.y; r[2] = (f16)u.z; r[3] = (f16)u.w;
    r[4] = (f16)v.x; r[5] = (f16)v.y; r[6] = (f16)v.z; r[7] = (f16)v.w;
    return r;
}

// q pre-scale: 1/sqrt(64) * log2(e) so softmax is exp2(s)
#define Q_SCALE 0.180336880111f

// ---------------------------------------------------------------------------
// pre_pass: blocks 0..2047 grid-stride cvt x->x16, qkv_w->w16;
//           blocks 2048..2051 per-batch mask scan -> gpos (valid t list), nkv.
// ---------------------------------------------------------------------------
__global__ __launch_bounds__(256) void pre_pass(
    const float* __restrict__ x, const float* __restrict__ qw,
    const int* __restrict__ mask, f16* __restrict__ x16,
    f16* __restrict__ w16, int* __restrict__ gpos, int* __restrict__ nkv)
{
    const int blk = blockIdx.x;
    if (blk >= 2048) {                 // scan: wave 0 of blocks 2048..2051
        const int b = blk - 2048;
        if (threadIdx.x < 64) {
            const int lane = threadIdx.x;
            const int* mb = mask + b * 2048;
            int run = 0;
            for (int c = 0; c < 2048; c += 64) {
                int v = (mb[c + lane] != 0) ? 1 : 0;
                unsigned long long bits = __ballot(v);
                int pre = __popcll(bits & ((1ull << lane) - 1ull));
                if (v) gpos[b * 2048 + run + pre] = c + lane;
                run += __popcll(bits);
            }
            if (lane == 0) nkv[b] = run;
        }
        return;
    }
    const int nx8 = 8192 * 1024 / 8;   // 1,048,576 groups of 8
    const int nw8 = 3072 * 1024 / 8;   //   393,216
    int idx = blk * 256 + threadIdx.x;
    const int stride = 2048 * 256;
    for (int i = idx; i < nx8 + nw8; i += stride) {
        const float* s; f16* d;
        if (i < nx8) { size_t o = (size_t)i * 8;          s = x  + o; d = x16 + o; }
        else         { size_t o = (size_t)(i - nx8) * 8;  s = qw + o; d = w16 + o; }
        float4 u = *(const float4*)s;
        float4 v = *(const float4*)(s + 4);
        *(f16x8*)d = cvt8(u, v);
    }
}

// ---------------------------------------------------------------------------
// cvt_f32_f16: vectorized fp32 -> fp16 (used for out_w after attn).
// ---------------------------------------------------------------------------
__global__ __launch_bounds__(256) void cvt_f32_f16(
    const float* __restrict__ src, f16* __restrict__ dst, int n8)
{
    int idx = blockIdx.x * 256 + threadIdx.x;
    int stride = gridDim.x * 256;
    for (int i = idx; i < n8; i += stride) {
        size_t o = (size_t)i * 8;
        float4 u = *(const float4*)&src[o];
        float4 v = *(const float4*)&src[o + 4];
        *(f16x8*)&dst[o] = cvt8(u, v);
    }
}

// ---------------------------------------------------------------------------
// gemm_qkv: grid (24,64). bx<8: Q over all rows. bx>=8: K/V over COMPACTED
// rows (gathered via gpos). 128x128 tile, BK=64, double-buffered
// global_load_lds with COUNTED vmcnt + raw barriers (no drain in loop).
// ---------------------------------------------------------------------------
__global__ __launch_bounds__(256) void gemm_qkv_f16(
    const f16* __restrict__ x16, const f16* __restrict__ w16,
    const float* __restrict__ bias, const int* __restrict__ gpos,
    const int* __restrict__ nkv, f16* __restrict__ q_g,
    f16* __restrict__ k_g, f16* __restrict__ vt_g)
{
    constexpr int BK = 64, K = 1024, NT = K / BK;
    __shared__ f16 As[2][128 * BK], Bs[2][128 * BK];   // 64 KB total

    const int tid  = threadIdx.x;
    const int lane = tid & 63, wave = tid >> 6;
    const int wy = wave >> 1, wx = wave & 1;
    const int lrow = lane & 15, quad = lane >> 4;
    const int srow = lane >> 3;       // row within 8-row DMA group
    const int sgrp = lane & 7;        // LDS 16B-group
    const int x0 = ((quad)     ^ (lrow & 7)) * 8;
    const int x1 = ((4 + quad) ^ (lrow & 7)) * 8;

    const int bx = blockIdx.x, by = blockIdx.y;
    const int z = (bx >= 8);
    int b_kv = 0, mt = 0, nk = 0, nbase, n0;
    if (!z) {
        nbase = 0; n0 = bx * 128;
    } else {
        b_kv = by >> 4; mt = by & 15;
        nk = nkv[b_kv];
        if (mt * 128 >= nk) return;
        nbase = 1024; n0 = (bx - 8) * 128;
    }

    // per-thread staged-row base addrs, fixed across the whole K-loop
    const f16* arow[4];
    const f16* brow[4];
#pragma unroll
    for (int j = 0; j < 4; ++j) {
        int rit = (wave * 4 + j) * 8 + srow;     // row in tile [0,128)
        int trow;
        if (!z) {
            trow = by * 128 + rit;               // global row [0,8192)
        } else {
            int ct = mt * 128 + rit;
            int t = (ct < nk) ? gpos[b_kv * 2048 + ct] : 0;  // tail -> t=0 (finite)
            trow = b_kv * 2048 + t;
        }
        arow[j] = x16 + (size_t)trow * K + (sgrp ^ srow) * 8;
        brow[j] = w16 + (size_t)(nbase + n0 + rit) * K + (sgrp ^ srow) * 8;
    }

    auto stage = [&](int k0, int bsel) {      // 8 loads/thread
#pragma unroll
        for (int j = 0; j < 4; ++j) {
            int rg = wave * 4 + j;
            gload_lds16(arow[j] + k0, &As[bsel][rg * 512 + lane * 8]);
            gload_lds16(brow[j] + k0, &Bs[bsel][rg * 512 + lane * 8]);
        }
    };

    f32x4 acc[4][4] = {};

    // prologue: both buffers free -> stage tiles 0 and 1; wait only tile 0.
    stage(0, 0);
    stage(BK, 1);
    asm volatile("s_waitcnt vmcnt(8)" ::: "memory");   // tile0 (oldest 8) done
    __builtin_amdgcn_s_barrier();                       // tile0 visible to all

    for (int kt = 0; kt < NT; ++kt) {
        const int cur = kt & 1;

        f16x8 a0[4], a1[4], b0[4], b1[4];
#pragma unroll
        for (int i = 0; i < 4; ++i) {
            const int r = (wy * 64 + i * 16 + lrow) * BK;
            a0[i] = *(const f16x8*)&As[cur][r + x0];
            a1[i] = *(const f16x8*)&As[cur][r + x1];
        }
#pragma unroll
        for (int j = 0; j < 4; ++j) {
            const int r = (wx * 64 + j * 16 + lrow) * BK;
            b0[j] = *(const f16x8*)&Bs[cur][r + x0];
            b1[j] = *(const f16x8*)&Bs[cur][r + x1];
        }
        __builtin_amdgcn_s_setprio(1);
#pragma unroll
        for (int i = 0; i < 4; ++i)
#pragma unroll
            for (int j = 0; j < 4; ++j) {
                acc[i][j] = __builtin_amdgcn_mfma_f32_16x16x32_f16(a0[i], b0[j], acc[i][j], 0, 0, 0);
                acc[i][j] = __builtin_amdgcn_mfma_f32_16x16x32_f16(a1[i], b1[j], acc[i][j], 0, 0, 0);
            }
        __builtin_amdgcn_s_setprio(0);

        __builtin_amdgcn_s_barrier();       // #1: all waves done reading cur (NO drain)
        if (kt + 2 < NT) {
            stage((kt + 2) * BK, cur);      // refill cur; kt+1 loads are older
            asm volatile("s_waitcnt vmcnt(8)" ::: "memory");  // own kt+1 done
        } else {
            asm volatile("s_waitcnt vmcnt(0)" ::: "memory");  // tail: drain
        }
        __builtin_amdgcn_s_barrier();       // #2: tile kt+1 visible to ALL waves
    }

    // epilogue: C/D layout col=lane&15, row=quad*4+reg
    if (!z) {
#pragma unroll
        for (int i = 0; i < 4; ++i) {
            size_t row = (size_t)by * 128 + wy * 64 + i * 16 + quad * 4;
            int b = (int)(row >> 11);
            int t = (int)(row & 2047);
#pragma unroll
            for (int j = 0; j < 4; ++j) {
                int col = n0 + wx * 64 + j * 16 + lrow;
                float bb = bias[col];
                int hh = col >> 6, d = col & 63;
                size_t o = ((size_t)(b * 16 + hh) * 2048 + t) * 64 + d;
#pragma unroll
                for (int r = 0; r < 4; ++r)
                    q_g[o + (size_t)r * 64] = (f16)((acc[i][j][r] + bb) * Q_SCALE);
            }
        }
    } else {
        const int region = n0 >> 10;   // 0=k, 1=v (block-uniform)
#pragma unroll
        for (int i = 0; i < 4; ++i) {
            int ct = mt * 128 + wy * 64 + i * 16 + quad * 4;
#pragma unroll
            for (int j = 0; j < 4; ++j) {
                int col = n0 + wx * 64 + j * 16 + lrow;       // [0,2048)
                float bb = bias[1024 + col];
                int cl = col & 1023, hh = cl >> 6, d = cl & 63;
                size_t bh = (size_t)(b_kv * 16 + hh);
                if (region == 0) {
#pragma unroll
                    for (int r = 0; r < 4; ++r)
                        k_g[(bh * 2048 + ct + r) * 64 + d] = (f16)(acc[i][j][r] + bb);
                } else {
                    f16x4_t pv;
#pragma unroll
                    for (int r = 0; r < 4; ++r) pv[r] = (f16)(acc[i][j][r] + bb);
                    *(f16x4_t*)&vt_g[(bh * 64 + d) * 2048 + ct] = pv;
                }
            }
        }
    }
}

// ---------------------------------------------------------------------------
// GEMM2: out = att @ ow16^T + b. Verbatim round 7 (passing).
// ---------------------------------------------------------------------------
__global__ __launch_bounds__(256) void gemm2_f16(
    const f16* __restrict__ A16, const f16* __restrict__ Bw16,
    const float* __restrict__ bias, float* __restrict__ C,
    int M, int N, int K)
{
    constexpr int BK = 64;
    __shared__ f16 As[2][128 * BK], Bs[2][128 * BK];

    const int tid  = threadIdx.x;
    const int lane = tid & 63, wave = tid >> 6;
    const int wy = wave >> 1, wx = wave & 1;
    const int lrow = lane & 15, quad = lane >> 4;
    const size_t m0 = (size_t)blockIdx.y * 128;
    const size_t n0 = (size_t)blockIdx.x * 128;
    const int srow = lane >> 3, sgrp = lane & 7;
    const int x0 = ((quad)     ^ (lrow & 7)) * 8;
    const int x1 = ((4 + quad) ^ (lrow & 7)) * 8;

    const f16* arow[4];
    const f16* brow[4];
#pragma unroll
    for (int j = 0; j < 4; ++j) {
        int rit = (wave * 4 + j) * 8 + srow;
        arow[j] = A16  + (m0 + rit) * (size_t)K + (sgrp ^ srow) * 8;
        brow[j] = Bw16 + (n0 + rit) * (size_t)K + (sgrp ^ srow) * 8;
    }

    auto stage = [&](int k0, int bsel) {
#pragma unroll
        for (int j = 0; j < 4; ++j) {
            int rg = wave * 4 + j;
            gload_lds16(arow[j] + k0, &As[bsel][rg * 512 + lane * 8]);
            gload_lds16(brow[j] + k0, &Bs[bsel][rg * 512 + lane * 8]);
        }
    };

    f32x4 acc[4][4] = {};
    const int NT = K / BK;

    stage(0, 0);
    __syncthreads();

    for (int kt = 0; kt < NT; ++kt) {
        const int cur = kt & 1;
        if (kt + 1 < NT) stage((kt + 1) * BK, cur ^ 1);

        f16x8 a0[4], a1[4], b0[4], b1[4];
#pragma unroll
        for (int i = 0; i < 4; ++i) {
            const int r = (wy * 64 + i * 16 + lrow) * BK;
            a0[i] = *(const f16x8*)&As[cur][r + x0];
            a1[i] = *(const f16x8*)&As[cur][r + x1];
        }
#pragma unroll
        for (int j = 0; j < 4; ++j) {
            const int r = (wx * 64 + j * 16 + lrow) * BK;
            b0[j] = *(const f16x8*)&Bs[cur][r + x0];
            b1[j] = *(const f16x8*)&Bs[cur][r + x1];
        }
        __builtin_amdgcn_s_setprio(1);
#pragma unroll
        for (int i = 0; i < 4; ++i)
#pragma unroll
            for (int j = 0; j < 4; ++j) {
                acc[i][j] = __builtin_amdgcn_mfma_f32_16x16x32_f16(a0[i], b0[j], acc[i][j], 0, 0, 0);
                acc[i][j] = __builtin_amdgcn_mfma_f32_16x16x32_f16(a1[i], b1[j], acc[i][j], 0, 0, 0);
            }
        __builtin_amdgcn_s_setprio(0);

        __syncthreads();
    }

#pragma unroll
    for (int i = 0; i < 4; ++i) {
        size_t row = m0 + wy * 64 + i * 16 + quad * 4;
#pragma unroll
        for (int j = 0; j < 4; ++j) {
            size_t col = n0 + wx * 64 + j * 16 + lrow;
            float bb = bias[col];
#pragma unroll
            for (int r = 0; r < 4; ++r)
                C[(row + r) * N + col] = acc[i][j][r] + bb;
        }
    }
}

// ---------------------------------------------------------------------------
// Attention over COMPACTED keys (verbatim rounds 5-7 - passing). Tail keys
// [nkv, pad64) hold finite garbage (t=0 projections) - gated by rem.
// ---------------------------------------------------------------------------
__global__ __launch_bounds__(256) void attn_f16(
    const f16* __restrict__ q_g, const f16* __restrict__ k_g,
    const f16* __restrict__ vt_g, const int* __restrict__ nkv,
    f16* __restrict__ att, int B, int T)
{
    constexpr int LDP = 72;
    __shared__ f16 Ks_s[2][64 * 64];
    __shared__ f16 Vt_s[2][64 * 64];
    __shared__ f16 Pt[128 * LDP];

    const int tid  = threadIdx.x;
    const int lane = tid & 63, wave = tid >> 6;
    const int lrow = lane & 15, quad = lane >> 4;
    const int bid = ((int)blockIdx.x & 7) * 128 + ((int)blockIdx.x >> 3);
    const int qt = bid & 15;
    const int h  = (bid >> 4) & 15;
    const int b  = bid >> 8;
    const size_t base = (size_t)b * T;
    const size_t bh = (size_t)(b * 16 + h);
    const f16* qg_base = q_g  + bh * (2048 * 64);
    const f16* kg_base = k_g  + bh * (2048 * 64);
    const f16* vt_base = vt_g + bh * (64 * 2048);

    const int nk = nkv[b];
    const int ntiles = (nk + 63) >> 6;

    const int x0 = ((quad)     ^ (lrow & 7)) * 8;
    const int x1 = ((4 + quad) ^ (lrow & 7)) * 8;

    f16x8 aq[2][2];
#pragma unroll
    for (int qi = 0; qi < 2; ++qi)
#pragma unroll
        for (int ks = 0; ks < 2; ++ks)
            aq[qi][ks] = *(const f16x8*)&qg_base[
                (size_t)(qt * 128 + wave * 32 + qi * 16 + lrow) * 64 + ks * 32 + quad * 8];

    f32x4 oacc[2][4] = {};
    float l_part[2] = {0.f, 0.f};

    const int srow0 = (lane >> 3);
    const int sgrp  = (lane & 7);

    auto stage = [&](int kt, int bsel) {
        const f16* kT = kg_base + kt * 4096;
#pragma unroll
        for (int j = 0; j < 2; ++j) {
            int rg  = wave + j * 4;
            int row = rg * 8 + srow0;
            int grp = sgrp ^ (row & 7);
            gload_lds16(&kT[row * 64 + grp * 8], &Ks_s[bsel][rg * 512 + lane * 8]);
            gload_lds16(&vt_base[(size_t)row * 2048 + kt * 64 + grp * 8],
                        &Vt_s[bsel][rg * 512 + lane * 8]);
        }
    };

    stage(0, 0);
    __syncthreads();

    for (int kt = 0; kt < ntiles; ++kt) {
        const int cur = kt & 1;
        if (kt + 1 < ntiles) stage(kt + 1, cur ^ 1);

        const f16* Ks = Ks_s[cur];
        const f16* Vt = Vt_s[cur];

        f32x4 s[2][4];
        __builtin_amdgcn_s_setprio(1);
#pragma unroll
        for (int ni = 0; ni < 4; ++ni) {
            const int key = ni * 16 + lrow;
            f16x8 k0 = *(const f16x8*)&Ks[key * 64 + x0];
            f16x8 k1 = *(const f16x8*)&Ks[key * 64 + x1];
#pragma unroll
            for (int qi = 0; qi < 2; ++qi) {
                f32x4 t = {0.f, 0.f, 0.f, 0.f};
                t = __builtin_amdgcn_mfma_f32_16x16x32_f16(k0, aq[qi][0], t, 0, 0, 0);
                t = __builtin_amdgcn_mfma_f32_16x16x32_f16(k1, aq[qi][1], t, 0, 0, 0);
                s[qi][ni] = t;
            }
        }
        __builtin_amdgcn_s_setprio(0);

        const int rem = nk - kt * 64;
        auto softmax = [&](bool masked) {
#pragma unroll
            for (int qi = 0; qi < 2; ++qi)
#pragma unroll
                for (int ni = 0; ni < 4; ++ni) {
                    float p[4];
#pragma unroll
                    for (int r = 0; r < 4; ++r) {
                        float e = __builtin_amdgcn_exp2f(s[qi][ni][r]);
                        p[r] = (!masked || (ni * 16 + quad * 4 + r) < rem) ? e : 0.f;
                    }
                    l_part[qi] += (p[0] + p[1]) + (p[2] + p[3]);
                    f16x4_t pk;
#pragma unroll
                    for (int r = 0; r < 4; ++r) pk[r] = (f16)p[r];
                    *(f16x4_t*)&Pt[(wave * 32 + qi * 16 + lrow) * LDP + ni * 16 + quad * 4] = pk;
                }
        };
        if (rem >= 64) softmax(false); else softmax(true);

        f16x8 pf[2][2];
#pragma unroll
        for (int qi = 0; qi < 2; ++qi)
#pragma unroll
            for (int ks = 0; ks < 2; ++ks)
                pf[qi][ks] = *(const f16x8*)&Pt[(wave * 32 + qi * 16 + lrow) * LDP + ks * 32 + quad * 8];
        __builtin_amdgcn_s_setprio(1);
#pragma unroll
        for (int di = 0; di < 4; ++di) {
            const int d = di * 16 + lrow;
            f16x8 v0 = *(const f16x8*)&Vt[d * 64 + x0];
            f16x8 v1 = *(const f16x8*)&Vt[d * 64 + x1];
#pragma unroll
            for (int qi = 0; qi < 2; ++qi) {
                oacc[qi][di] = __builtin_amdgcn_mfma_f32_16x16x32_f16(v0, pf[qi][0], oacc[qi][di], 0, 0, 0);
                oacc[qi][di] = __builtin_amdgcn_mfma_f32_16x16x32_f16(v1, pf[qi][1], oacc[qi][di], 0, 0, 0);
            }
        }
        __builtin_amdgcn_s_setprio(0);

        __syncthreads();
    }

#pragma unroll
    for (int qi = 0; qi < 2; ++qi) {
        float v = l_part[qi];
        v += __shfl_xor(v, 16);
        v += __shfl_xor(v, 32);
        float inv = 1.f / v;
        int q = qt * 128 + wave * 32 + qi * 16 + lrow;
#pragma unroll
        for (int di = 0; di < 4; ++di) {
            f16x4_t o;
#pragma unroll
            for (int r = 0; r < 4; ++r) o[r] = (f16)(oacc[qi][di][r] * inv);
            *(f16x4_t*)&att[(base + q) * 1024 + h * 64 + di * 16 + quad * 4] = o;
        }
    }
}

// ---------------------------------------------------------------------------
extern "C" void kernel_launch(void* const* d_in, const int* in_sizes, int n_in,
                              void* d_out, int out_size, void* d_ws, size_t ws_size,
                              hipStream_t stream) {
    const float* x     = (const float*)d_in[0];   // [4,2048,1024]
    const int*   mask  = (const int*)d_in[1];     // [4,1,1,2048]
    const float* qkv_w = (const float*)d_in[2];   // [3072,1024]
    const float* qkv_b = (const float*)d_in[3];   // [3072]
    const float* out_w = (const float*)d_in[4];   // [1024,1024]
    const float* out_b = (const float*)d_in[5];   // [1024]
    float* out = (float*)d_out;                   // [4,2048,1024] fp32

    const int B = 4, T = 2048;
    const int M = B * T;                          // 8192
    char* ws = (char*)d_ws;
    f16* q_g = (f16*)(ws);                        // 16.78 MB [b,h,t,d] (pre-scaled)
    f16* k_g = (f16*)(ws + 16777216);             // 16.78 MB [b,h,ct,d] compacted
    f16* vt  = (f16*)(ws + 33554432);             // 16.78 MB [b,h,d,ct] compacted
    f16* att = (f16*)(ws + 50331648);             // 16.78 MB [t][1024]

    // d_out scratch (33.5 MB): x16 | w16 | gpos | nkv. All dead before gemm2
    // writes out. ow16 goes in q_g region (dead after attn).
    f16* x16 = (f16*)d_out;                       // 16.78 MB
    f16* w16 = (f16*)((char*)d_out + 16777216);   //  6.29 MB
    int* gpos = (int*)((char*)d_out + 23068672);  // 32 KB
    int* nkv  = gpos + 4 * 2048;                  // 16 B
    f16* ow16 = q_g;                              //  2.10 MB (after attn)

    dim3 blk(256);
    pre_pass<<<dim3(2052), blk, 0, stream>>>(x, qkv_w, mask, x16, w16, gpos, nkv);
    gemm_qkv_f16<<<dim3(24, 64), blk, 0, stream>>>(x16, w16, qkv_b, gpos, nkv, q_g, k_g, vt);
    attn_f16<<<dim3(B * 16 * 16), blk, 0, stream>>>(q_g, k_g, vt, nkv, att, B, T);
    cvt_f32_f16<<<dim3(512), blk, 0, stream>>>(out_w, ow16, 1024 * 1024 / 8);
    gemm2_f16<<<dim3(1024 / 128, M / 128), blk, 0, stream>>>(att, ow16, out_b, out, M, 1024, 1024);
}